// Round 1
// baseline (1011.819 us; speedup 1.0000x reference)
//
#include <hip/hip_runtime.h>

#define N_ 16384
#define E_ 131072
#define G_ 32
#define EPSF 1e-5f

// ---------------- workspace layout (bytes) ----------------
static const size_t OFF_INDEG = 0;          // int[N]        65536
static const size_t OFF_ROWS  = 65536;      // int[N+1]      (pad)
static const size_t OFF_CURSOR= 131584;     // int[N]
static const size_t OFF_CSR   = 197120;     // int[E]        524288
static const size_t OFF_DIS   = 721408;     // float[N]
static const size_t OFF_ES    = 786944;     // float[4N]
static const size_t OFF_ED    = 1049088;    // float[4N]
static const size_t OFF_BNS   = 1311232;    // float[512]
static const size_t OFF_BNQ   = 1313280;    // float[512]
static const size_t OFF_GB    = 1315328;    // int[33]
static const size_t OFF_POOL  = 1315584;    // float[32*1024]
static const size_t OFF_XA1   = 1446656;    // float[5N]
static const size_t OFF_H1    = 1774336;    // float[64N]   4 MB
static const size_t OFF_AGG   = 5968640;    // float[64N]   4 MB
static const size_t OFF_H2    = 10162944;   // float[128N]  8 MB
static const size_t OFF_H3    = 18551552;   // float[256N]  16 MB
static const size_t OFF_HGAT  = 35328768;   // float[1024N] 64 MB
static const size_t OFF_XA4   = OFF_HGAT;            // reuse (hgat dead)
static const size_t OFF_H4    = OFF_HGAT + 16777216; // reuse
// total ≈ 97.7 MB

// ---------------- graph structure ----------------
__global__ void k_indeg(const int* __restrict__ dst, int* __restrict__ indeg) {
    int e = blockIdx.x * 256 + threadIdx.x;
    if (e < E_) atomicAdd(&indeg[dst[e]], 1);
}

__global__ void k_dis(const int* __restrict__ indeg, float* __restrict__ dis) {
    int i = blockIdx.x * 256 + threadIdx.x;
    if (i < N_) dis[i] = rsqrtf((float)indeg[i] + 1.0f);
}

__global__ __launch_bounds__(1024) void k_scan(const int* __restrict__ indeg,
                                               int* __restrict__ rows) {
    __shared__ int part[1024];
    int t = threadIdx.x;
    int base = t * 16;
    int local[16];
    int s = 0;
#pragma unroll
    for (int i = 0; i < 16; ++i) { local[i] = indeg[base + i]; s += local[i]; }
    part[t] = s;
    __syncthreads();
    for (int off = 1; off < 1024; off <<= 1) {
        int v = (t >= off) ? part[t - off] : 0;
        __syncthreads();
        part[t] += v;
        __syncthreads();
    }
    int run = (t == 0) ? 0 : part[t - 1];
#pragma unroll
    for (int i = 0; i < 16; ++i) { rows[base + i] = run; run += local[i]; }
    if (t == 1023) rows[N_] = run;
}

__global__ void k_fill(const int* __restrict__ src, const int* __restrict__ dst,
                       int* __restrict__ cursor, int* __restrict__ csr) {
    int e = blockIdx.x * 256 + threadIdx.x;
    if (e < E_) {
        int p = atomicAdd(&cursor[dst[e]], 1);
        csr[p] = src[e];
    }
}

__global__ void k_gbounds(const int* __restrict__ batch, int* __restrict__ gb) {
    int g = threadIdx.x;
    if (g > G_) return;
    if (g == G_) { gb[G_] = N_; return; }
    int lo = 0, hi = N_;
    while (lo < hi) { int mid = (lo + hi) >> 1; if (batch[mid] < g) lo = mid + 1; else hi = mid; }
    gb[g] = lo;
}

// ---------------- layer 1: GCN(5->64) ----------------
__global__ void k_gcn1_agg(const float* __restrict__ x, const float* __restrict__ dis,
                           const int* __restrict__ rows, const int* __restrict__ csr,
                           float* __restrict__ xa) {
    int i = blockIdx.x * 256 + threadIdx.x;
    if (i >= N_) return;
    float di = dis[i];
    float a0 = x[i*5+0]*di*di, a1 = x[i*5+1]*di*di, a2 = x[i*5+2]*di*di,
          a3 = x[i*5+3]*di*di, a4 = x[i*5+4]*di*di;
    int e0 = rows[i], e1 = rows[i+1];
    for (int e = e0; e < e1; ++e) {
        int s = csr[e];
        float w = dis[s] * di;
        a0 += x[s*5+0]*w; a1 += x[s*5+1]*w; a2 += x[s*5+2]*w;
        a3 += x[s*5+3]*w; a4 += x[s*5+4]*w;
    }
    xa[i*5+0]=a0; xa[i*5+1]=a1; xa[i*5+2]=a2; xa[i*5+3]=a3; xa[i*5+4]=a4;
}

__global__ void k_mm5(const float* __restrict__ xa, const float* __restrict__ w,
                      const float* __restrict__ b, float* __restrict__ out) {
    int idx = blockIdx.x * 256 + threadIdx.x;   // N*64
    int n = idx >> 6, m = idx & 63;
    float s = b[m];
#pragma unroll
    for (int k = 0; k < 5; ++k) s += xa[n*5+k] * w[k*64+m];
    out[idx] = s;
}

// ---------------- batchnorm ----------------
__global__ void k_bn_stats(const float* __restrict__ x, float* __restrict__ sum,
                           float* __restrict__ sumsq, int C, int rowsPerBlock) {
    int t = threadIdx.x;
    size_t base = (size_t)blockIdx.x * rowsPerBlock * C;
    size_t end  = base + (size_t)rowsPerBlock * C;
    if (C == 512) {
        float s0=0,q0=0,s1=0,q1=0;
        for (size_t f = base + t; f < end; f += 512) {
            float v = x[f];     s0 += v; q0 += v*v;
            float w = x[f+256]; s1 += w; q1 += w*w;
        }
        atomicAdd(&sum[t], s0);      atomicAdd(&sumsq[t], q0);
        atomicAdd(&sum[t+256], s1);  atomicAdd(&sumsq[t+256], q1);
    } else {
        float s0=0,q0=0;
        for (size_t f = base + t; f < end; f += 256) {
            float v = x[f]; s0 += v; q0 += v*v;
        }
        __shared__ float ls[256], lq[256];
        ls[t]=s0; lq[t]=q0;
        __syncthreads();
        if (t < C) {
            for (int j = t + C; j < 256; j += C) { s0 += ls[j]; q0 += lq[j]; }
            atomicAdd(&sum[t], s0); atomicAdd(&sumsq[t], q0);
        }
    }
}

__global__ void k_bn_apply(float* __restrict__ h, const float* __restrict__ sum,
                           const float* __restrict__ sumsq, const float* __restrict__ g,
                           const float* __restrict__ b, int C, int total) {
    int idx = blockIdx.x * 256 + threadIdx.x;
    if (idx >= total) return;
    int c = idx & (C - 1);
    const float invN = 1.0f / (float)N_;
    float mu  = sum[c] * invN;
    float var = sumsq[c] * invN - mu * mu;
    float v = (h[idx] - mu) * rsqrtf(var + EPSF) * g[c] + b[c];
    h[idx] = v > 0.f ? v : 0.f;
}

// ---------------- SAGE aggregate (mean) ----------------
__global__ void k_sage_agg(const float* __restrict__ h1, const int* __restrict__ rows,
                           const int* __restrict__ csr, float* __restrict__ agg) {
    int i = blockIdx.x * 4 + (threadIdx.x >> 6);
    int c = threadIdx.x & 63;
    int e0 = rows[i], e1 = rows[i+1];
    float s = 0.f;
    for (int e = e0; e < e1; ++e) s += h1[(size_t)csr[e]*64 + c];
    agg[(size_t)i*64 + c] = s / fmaxf((float)(e1 - e0), 1.0f);
}

// ---------------- generic tiled SGEMM: C[n,m] (+)= A[n,k] B[k,m] ----------------
__global__ __launch_bounds__(256) void k_gemm(const float* __restrict__ A,
                                              const float* __restrict__ B,
                                              const float* __restrict__ bias,
                                              float* __restrict__ C,
                                              int K, int M, int accum) {
    __shared__ float As[16][68];
    __shared__ float Bs[16][68];
    int tid = threadIdx.x;
    int tx = tid & 15, ty = tid >> 4;
    int row0 = blockIdx.y * 64, col0 = blockIdx.x * 64;
    float acc[4][4];
#pragma unroll
    for (int i = 0; i < 4; ++i)
#pragma unroll
        for (int j = 0; j < 4; ++j) acc[i][j] = 0.f;
    int lka = tid & 15, lra = tid >> 4;
    int lcb = tid & 63, lkb = tid >> 6;
    for (int k0 = 0; k0 < K; k0 += 16) {
#pragma unroll
        for (int it = 0; it < 4; ++it)
            As[lka][lra + it*16] = A[(size_t)(row0 + lra + it*16)*K + k0 + lka];
#pragma unroll
        for (int it = 0; it < 4; ++it)
            Bs[lkb + it*4][lcb] = B[(size_t)(k0 + lkb + it*4)*M + col0 + lcb];
        __syncthreads();
#pragma unroll
        for (int k = 0; k < 16; ++k) {
            float a0 = As[k][ty*4+0], a1 = As[k][ty*4+1],
                  a2 = As[k][ty*4+2], a3 = As[k][ty*4+3];
            float b0 = Bs[k][tx*4+0], b1 = Bs[k][tx*4+1],
                  b2 = Bs[k][tx*4+2], b3 = Bs[k][tx*4+3];
            acc[0][0] += a0*b0; acc[0][1] += a0*b1; acc[0][2] += a0*b2; acc[0][3] += a0*b3;
            acc[1][0] += a1*b0; acc[1][1] += a1*b1; acc[1][2] += a1*b2; acc[1][3] += a1*b3;
            acc[2][0] += a2*b0; acc[2][1] += a2*b1; acc[2][2] += a2*b2; acc[2][3] += a2*b3;
            acc[3][0] += a3*b0; acc[3][1] += a3*b1; acc[3][2] += a3*b2; acc[3][3] += a3*b3;
        }
        __syncthreads();
    }
#pragma unroll
    for (int i = 0; i < 4; ++i) {
        int r = row0 + ty*4 + i;
#pragma unroll
        for (int j = 0; j < 4; ++j) {
            int c = col0 + tx*4 + j;
            size_t idx = (size_t)r*M + c;
            float v = acc[i][j];
            if (bias)  v += bias[c];
            if (accum) v += C[idx];
            C[idx] = v;
        }
    }
}

// ---------------- GAT ----------------
__global__ __launch_bounds__(256) void k_gat_attn(const float* __restrict__ hg,
                                                  const float* __restrict__ asrc,
                                                  const float* __restrict__ adst,
                                                  float* __restrict__ es,
                                                  float* __restrict__ ed) {
    __shared__ float red[256];
    int i = blockIdx.x, t = threadIdx.x;
    for (int h = 0; h < 4; ++h) {
        float hv = hg[(size_t)i*1024 + h*256 + t];
        float pe = hv * asrc[h*256 + t];
        red[t] = pe; __syncthreads();
        for (int s = 128; s > 0; s >>= 1) { if (t < s) red[t] += red[t+s]; __syncthreads(); }
        if (t == 0) es[i*4 + h] = red[0];
        __syncthreads();
        float pd = hv * adst[h*256 + t];
        red[t] = pd; __syncthreads();
        for (int s = 128; s > 0; s >>= 1) { if (t < s) red[t] += red[t+s]; __syncthreads(); }
        if (t == 0) ed[i*4 + h] = red[0];
        __syncthreads();
    }
}

#define GCHUNK 1024
__global__ __launch_bounds__(256) void k_gat_agg(const float* __restrict__ hg,
                                                 const float* __restrict__ es,
                                                 const float* __restrict__ ed,
                                                 const int* __restrict__ rows,
                                                 const int* __restrict__ csr,
                                                 const float* __restrict__ gbias,
                                                 float* __restrict__ out) {
    __shared__ float se[GCHUNK * 4];
    __shared__ int ssrc[GCHUNK];
    int i = blockIdx.x, t = threadIdx.x;
    float edv[4], m[4], z[4], acc[4];
#pragma unroll
    for (int h = 0; h < 4; ++h) edv[h] = ed[i*4 + h];
#pragma unroll
    for (int h = 0; h < 4; ++h) {                 // self-loop
        float e = es[i*4 + h] + edv[h];
        e = e >= 0.f ? e : 0.2f * e;
        m[h] = e; z[h] = 1.f;
        acc[h] = hg[(size_t)i*1024 + h*256 + t];
    }
    int e0 = rows[i], e1 = rows[i+1];
    for (int c0 = e0; c0 < e1; c0 += GCHUNK) {
        int cn = min(GCHUNK, e1 - c0);
        for (int j = t; j < cn; j += 256) {
            int s = csr[c0 + j];
            ssrc[j] = s;
#pragma unroll
            for (int h = 0; h < 4; ++h) {
                float e = es[s*4 + h] + edv[h];
                se[j*4 + h] = e >= 0.f ? e : 0.2f * e;
            }
        }
        __syncthreads();
        float nm[4] = {m[0], m[1], m[2], m[3]};
        for (int j = 0; j < cn; ++j) {
#pragma unroll
            for (int h = 0; h < 4; ++h) nm[h] = fmaxf(nm[h], se[j*4 + h]);
        }
#pragma unroll
        for (int h = 0; h < 4; ++h) {
            float sc = __expf(m[h] - nm[h]);
            z[h] *= sc; acc[h] *= sc; m[h] = nm[h];
        }
        for (int j = 0; j < cn; ++j) {
            int s = ssrc[j];
#pragma unroll
            for (int h = 0; h < 4; ++h) {
                float a = __expf(se[j*4 + h] - m[h]);
                z[h] += a;
                acc[h] += a * hg[(size_t)s*1024 + h*256 + t];
            }
        }
        __syncthreads();
    }
    float o = 0.25f * (acc[0]/z[0] + acc[1]/z[1] + acc[2]/z[2] + acc[3]/z[3]);
    out[(size_t)i*256 + t] = o + gbias[t];
}

// ---------------- layer 4: GCN(256->512) aggregate ----------------
__global__ __launch_bounds__(256) void k_gcn4_agg(const float* __restrict__ h3,
                                                  const float* __restrict__ dis,
                                                  const int* __restrict__ rows,
                                                  const int* __restrict__ csr,
                                                  float* __restrict__ xa) {
    int i = blockIdx.x, t = threadIdx.x;
    float di = dis[i];
    float a = h3[(size_t)i*256 + t] * di * di;
    int e0 = rows[i], e1 = rows[i+1];
    for (int e = e0; e < e1; ++e) {
        int s = csr[e];
        a += h3[(size_t)s*256 + t] * (dis[s] * di);
    }
    xa[(size_t)i*256 + t] = a;
}

// ---------------- pooling ----------------
__global__ void k_pool(const float* __restrict__ h4, const int* __restrict__ gb,
                       float* __restrict__ pooled) {
    int g = blockIdx.y;
    int t = threadIdx.x;
    int r0g = gb[g], r1g = gb[g+1];
    int n = r1g - r0g;
    if (n <= 0) return;
    int per = (n + 15) >> 4;
    int r0 = r0g + blockIdx.x * per;
    int r1 = min(r0 + per, r1g);
    if (r0 >= r1) return;
    float s0=0.f, s1=0.f, m0=0.f, m1=0.f;   // h4 >= 0 post-ReLU: max init 0 valid
    for (int r = r0; r < r1; ++r) {
        float v = h4[(size_t)r*512 + t];       s0 += v; m0 = fmaxf(m0, v);
        float w = h4[(size_t)r*512 + 256 + t]; s1 += w; m1 = fmaxf(m1, w);
    }
    atomicAdd(&pooled[g*1024 + t], s0);
    atomicAdd(&pooled[g*1024 + 256 + t], s1);
    atomicMax((int*)&pooled[g*1024 + 512 + t],  __float_as_int(m0));
    atomicMax((int*)&pooled[g*1024 + 768 + t],  __float_as_int(m1));
}

__global__ void k_pool_fin(float* __restrict__ pooled, const int* __restrict__ gb) {
    int g = blockIdx.x, t = threadIdx.x;    // 512 threads
    int cnt = gb[g+1] - gb[g];
    pooled[g*1024 + t] *= 1.0f / fmaxf((float)cnt, 1.0f);
}

// ---------------- FC ----------------
__global__ __launch_bounds__(256) void k_fc(const float* __restrict__ pooled,
                                            const float* __restrict__ w,
                                            const float* __restrict__ b,
                                            float* __restrict__ out) {
    __shared__ float pr[1024];
    int g = blockIdx.y;
    int m = blockIdx.x * 256 + threadIdx.x;
    for (int k = threadIdx.x; k < 1024; k += 256) pr[k] = pooled[g*1024 + k];
    __syncthreads();
    float acc = b[m];
#pragma unroll 4
    for (int k = 0; k < 1024; ++k) acc += pr[k] * w[k*1024 + m];
    out[g*1024 + m] = acc;
}

// ---------------- host ----------------
extern "C" void kernel_launch(void* const* d_in, const int* in_sizes, int n_in,
                              void* d_out, int out_size, void* d_ws, size_t ws_size,
                              hipStream_t stream) {
    (void)in_sizes; (void)n_in; (void)out_size; (void)ws_size;
    const float* x       = (const float*)d_in[0];
    const int*   ei      = (const int*)d_in[1];
    const int*   batch   = (const int*)d_in[2];
    const float* gcn1_w  = (const float*)d_in[3];
    const float* gcn1_b  = (const float*)d_in[4];
    const float* sage_wl = (const float*)d_in[5];
    const float* sage_wr = (const float*)d_in[6];
    const float* sage_b  = (const float*)d_in[7];
    const float* gat_w   = (const float*)d_in[8];
    const float* gat_as  = (const float*)d_in[9];
    const float* gat_ad  = (const float*)d_in[10];
    const float* gat_b   = (const float*)d_in[11];
    const float* gcn4_w  = (const float*)d_in[12];
    const float* gcn4_b  = (const float*)d_in[13];
    const float* bn1_g   = (const float*)d_in[14];
    const float* bn1_b   = (const float*)d_in[15];
    const float* bn2_g   = (const float*)d_in[16];
    const float* bn2_b   = (const float*)d_in[17];
    const float* bn3_g   = (const float*)d_in[18];
    const float* bn3_b   = (const float*)d_in[19];
    const float* bn4_g   = (const float*)d_in[20];
    const float* bn4_b   = (const float*)d_in[21];
    const float* fc_w    = (const float*)d_in[22];
    const float* fc_b    = (const float*)d_in[23];
    float* out = (float*)d_out;

    char* w8 = (char*)d_ws;
    int*   indeg  = (int*)(w8 + OFF_INDEG);
    int*   rows   = (int*)(w8 + OFF_ROWS);
    int*   cursor = (int*)(w8 + OFF_CURSOR);
    int*   csr    = (int*)(w8 + OFF_CSR);
    float* dis    = (float*)(w8 + OFF_DIS);
    float* es     = (float*)(w8 + OFF_ES);
    float* ed     = (float*)(w8 + OFF_ED);
    float* bns    = (float*)(w8 + OFF_BNS);
    float* bnq    = (float*)(w8 + OFF_BNQ);
    int*   gb     = (int*)(w8 + OFF_GB);
    float* pooled = (float*)(w8 + OFF_POOL);
    float* xa1    = (float*)(w8 + OFF_XA1);
    float* h1     = (float*)(w8 + OFF_H1);
    float* agg    = (float*)(w8 + OFF_AGG);
    float* h2     = (float*)(w8 + OFF_H2);
    float* h3     = (float*)(w8 + OFF_H3);
    float* hgat   = (float*)(w8 + OFF_HGAT);
    float* xa4    = (float*)(w8 + OFF_XA4);
    float* h4     = (float*)(w8 + OFF_H4);

    const int* srcE = ei;        // edge_index[0,:]
    const int* dstE = ei + E_;   // edge_index[1,:]

    // ---- graph structure ----
    hipMemsetAsync(indeg, 0, N_ * sizeof(int), stream);
    k_indeg<<<E_/256, 256, 0, stream>>>(dstE, indeg);
    k_dis<<<N_/256, 256, 0, stream>>>(indeg, dis);
    k_scan<<<1, 1024, 0, stream>>>(indeg, rows);
    hipMemcpyAsync(cursor, rows, N_ * sizeof(int), hipMemcpyDeviceToDevice, stream);
    k_fill<<<E_/256, 256, 0, stream>>>(srcE, dstE, cursor, csr);
    k_gbounds<<<1, 64, 0, stream>>>(batch, gb);

    // ---- layer 1: GCN 5->64, BN, ReLU ----
    k_gcn1_agg<<<N_/256, 256, 0, stream>>>(x, dis, rows, csr, xa1);
    k_mm5<<<(N_*64)/256, 256, 0, stream>>>(xa1, gcn1_w, gcn1_b, h1);
    hipMemsetAsync(bns, 0, 4096, stream);
    k_bn_stats<<<32, 256, 0, stream>>>(h1, bns, bnq, 64, N_/32);
    k_bn_apply<<<(N_*64)/256, 256, 0, stream>>>(h1, bns, bnq, bn1_g, bn1_b, 64, N_*64);

    // ---- layer 2: SAGE 64->128, BN, ReLU ----
    k_sage_agg<<<N_/4, 256, 0, stream>>>(h1, rows, csr, agg);
    {
        dim3 grid(128/64, N_/64);
        k_gemm<<<grid, 256, 0, stream>>>(agg, sage_wl, nullptr, h2, 64, 128, 0);
        k_gemm<<<grid, 256, 0, stream>>>(h1, sage_wr, sage_b, h2, 64, 128, 1);
    }
    hipMemsetAsync(bns, 0, 4096, stream);
    k_bn_stats<<<32, 256, 0, stream>>>(h2, bns, bnq, 128, N_/32);
    k_bn_apply<<<(N_*128)/256, 256, 0, stream>>>(h2, bns, bnq, bn2_g, bn2_b, 128, N_*128);

    // ---- layer 3: GAT 128->4x256 (head-mean -> 256), BN, ReLU ----
    {
        dim3 grid(1024/64, N_/64);
        k_gemm<<<grid, 256, 0, stream>>>(h2, gat_w, nullptr, hgat, 128, 1024, 0);
    }
    k_gat_attn<<<N_, 256, 0, stream>>>(hgat, gat_as, gat_ad, es, ed);
    k_gat_agg<<<N_, 256, 0, stream>>>(hgat, es, ed, rows, csr, gat_b, h3);
    hipMemsetAsync(bns, 0, 4096, stream);
    k_bn_stats<<<32, 256, 0, stream>>>(h3, bns, bnq, 256, N_/32);
    k_bn_apply<<<(N_*256)/256, 256, 0, stream>>>(h3, bns, bnq, bn3_g, bn3_b, 256, N_*256);

    // ---- layer 4: GCN 256->512, BN, ReLU ----
    k_gcn4_agg<<<N_, 256, 0, stream>>>(h3, dis, rows, csr, xa4);
    {
        dim3 grid(512/64, N_/64);
        k_gemm<<<grid, 256, 0, stream>>>(xa4, gcn4_w, gcn4_b, h4, 256, 512, 0);
    }
    hipMemsetAsync(bns, 0, 4096, stream);
    k_bn_stats<<<32, 256, 0, stream>>>(h4, bns, bnq, 512, N_/32);
    k_bn_apply<<<(N_*512)/256, 256, 0, stream>>>(h4, bns, bnq, bn4_g, bn4_b, 512, N_*512);

    // ---- pooling (mean | max) -> [32,1024] ----
    hipMemsetAsync(pooled, 0, 32 * 1024 * sizeof(float), stream);
    {
        dim3 grid(16, G_);
        k_pool<<<grid, 256, 0, stream>>>(h4, gb, pooled);
    }
    k_pool_fin<<<G_, 512, 0, stream>>>(pooled, gb);

    // ---- FC 1024->1024 ----
    {
        dim3 grid(1024/256, G_);
        k_fc<<<grid, 256, 0, stream>>>(pooled, fc_w, fc_b, out);
    }
}

// Round 2
// 715.439 us; speedup vs baseline: 1.4143x; 1.4143x over previous
//
#include <hip/hip_runtime.h>

#define N_ 16384
#define E_ 131072
#define G_ 32
#define EPSF 1e-5f

// ---------------- workspace layout (bytes) ----------------
static const size_t OFF_INDEG = 0;          // int[N]        65536
static const size_t OFF_ROWS  = 65536;      // int[N+1]      (pad)
static const size_t OFF_CURSOR= 131584;     // int[N]
static const size_t OFF_CSR   = 197120;     // int[E]        524288
static const size_t OFF_DIS   = 721408;     // float[N]
static const size_t OFF_ES    = 786944;     // float[4N]
static const size_t OFF_ED    = 1049088;    // float[4N]
static const size_t OFF_BNS   = 1311232;    // float[512]
static const size_t OFF_BNQ   = 1313280;    // float[512]
static const size_t OFF_GB    = 1315328;    // int[33]
static const size_t OFF_POOL  = 1315584;    // float[32*1024]
static const size_t OFF_XA1   = 1446656;    // float[5N]
static const size_t OFF_H1    = 1774336;    // float[64N]   4 MB
static const size_t OFF_AGG   = 5968640;    // float[64N]   4 MB
static const size_t OFF_H2    = 10162944;   // float[128N]  8 MB
static const size_t OFF_H3    = 18551552;   // float[256N]  16 MB
static const size_t OFF_HGAT  = 35328768;   // float[1024N] 64 MB
static const size_t OFF_XA4   = OFF_HGAT;            // reuse (hgat dead)
static const size_t OFF_H4    = OFF_HGAT + 16777216; // reuse
// total ≈ 97.7 MB

// ---------------- graph structure ----------------
__global__ void k_indeg(const int* __restrict__ dst, int* __restrict__ indeg) {
    int e = blockIdx.x * 256 + threadIdx.x;
    if (e < E_) atomicAdd(&indeg[dst[e]], 1);
}

__global__ void k_dis(const int* __restrict__ indeg, float* __restrict__ dis) {
    int i = blockIdx.x * 256 + threadIdx.x;
    if (i < N_) dis[i] = rsqrtf((float)indeg[i] + 1.0f);
}

__global__ __launch_bounds__(1024) void k_scan(const int* __restrict__ indeg,
                                               int* __restrict__ rows) {
    __shared__ int part[1024];
    int t = threadIdx.x;
    int base = t * 16;
    int local[16];
    int s = 0;
#pragma unroll
    for (int i = 0; i < 16; ++i) { local[i] = indeg[base + i]; s += local[i]; }
    part[t] = s;
    __syncthreads();
    for (int off = 1; off < 1024; off <<= 1) {
        int v = (t >= off) ? part[t - off] : 0;
        __syncthreads();
        part[t] += v;
        __syncthreads();
    }
    int run = (t == 0) ? 0 : part[t - 1];
#pragma unroll
    for (int i = 0; i < 16; ++i) { rows[base + i] = run; run += local[i]; }
    if (t == 1023) rows[N_] = run;
}

__global__ void k_fill(const int* __restrict__ src, const int* __restrict__ dst,
                       int* __restrict__ cursor, int* __restrict__ csr) {
    int e = blockIdx.x * 256 + threadIdx.x;
    if (e < E_) {
        int p = atomicAdd(&cursor[dst[e]], 1);
        csr[p] = src[e];
    }
}

__global__ void k_gbounds(const int* __restrict__ batch, int* __restrict__ gb) {
    int g = threadIdx.x;
    if (g > G_) return;
    if (g == G_) { gb[G_] = N_; return; }
    int lo = 0, hi = N_;
    while (lo < hi) { int mid = (lo + hi) >> 1; if (batch[mid] < g) lo = mid + 1; else hi = mid; }
    gb[g] = lo;
}

// ---------------- layer 1: GCN(5->64) ----------------
__global__ void k_gcn1_agg(const float* __restrict__ x, const float* __restrict__ dis,
                           const int* __restrict__ rows, const int* __restrict__ csr,
                           float* __restrict__ xa) {
    int i = blockIdx.x * 256 + threadIdx.x;
    if (i >= N_) return;
    float di = dis[i];
    float a0 = x[i*5+0]*di*di, a1 = x[i*5+1]*di*di, a2 = x[i*5+2]*di*di,
          a3 = x[i*5+3]*di*di, a4 = x[i*5+4]*di*di;
    int e0 = rows[i], e1 = rows[i+1];
    for (int e = e0; e < e1; ++e) {
        int s = csr[e];
        float w = dis[s] * di;
        a0 += x[s*5+0]*w; a1 += x[s*5+1]*w; a2 += x[s*5+2]*w;
        a3 += x[s*5+3]*w; a4 += x[s*5+4]*w;
    }
    xa[i*5+0]=a0; xa[i*5+1]=a1; xa[i*5+2]=a2; xa[i*5+3]=a3; xa[i*5+4]=a4;
}

__global__ void k_mm5(const float* __restrict__ xa, const float* __restrict__ w,
                      const float* __restrict__ b, float* __restrict__ out) {
    int idx = blockIdx.x * 256 + threadIdx.x;   // N*64
    int n = idx >> 6, m = idx & 63;
    float s = b[m];
#pragma unroll
    for (int k = 0; k < 5; ++k) s += xa[n*5+k] * w[k*64+m];
    out[idx] = s;
}

// ---------------- batchnorm ----------------
// grid = 512 blocks (rowsPerBlock = 32): round-1 profile showed 32-block
// launch at 1.3% occupancy / 116 GB/s was ~half of total runtime.
__global__ void k_bn_stats(const float* __restrict__ x, float* __restrict__ sum,
                           float* __restrict__ sumsq, int C, int rowsPerBlock) {
    int t = threadIdx.x;
    size_t base = (size_t)blockIdx.x * rowsPerBlock * C;
    size_t end  = base + (size_t)rowsPerBlock * C;
    if (C == 512) {
        float s0=0,q0=0,s1=0,q1=0;
        for (size_t f = base + t; f < end; f += 512) {
            float v = x[f];     s0 += v; q0 += v*v;
            float w = x[f+256]; s1 += w; q1 += w*w;
        }
        atomicAdd(&sum[t], s0);      atomicAdd(&sumsq[t], q0);
        atomicAdd(&sum[t+256], s1);  atomicAdd(&sumsq[t+256], q1);
    } else {
        float s0=0,q0=0;
        for (size_t f = base + t; f < end; f += 256) {
            float v = x[f]; s0 += v; q0 += v*v;
        }
        __shared__ float ls[256], lq[256];
        ls[t]=s0; lq[t]=q0;
        __syncthreads();
        if (t < C) {
            for (int j = t + C; j < 256; j += C) { s0 += ls[j]; q0 += lq[j]; }
            atomicAdd(&sum[t], s0); atomicAdd(&sumsq[t], q0);
        }
    }
}

__global__ void k_bn_apply(float* __restrict__ h, const float* __restrict__ sum,
                           const float* __restrict__ sumsq, const float* __restrict__ g,
                           const float* __restrict__ b, int C, int total) {
    int idx = blockIdx.x * 256 + threadIdx.x;
    if (idx >= total) return;
    int c = idx & (C - 1);
    const float invN = 1.0f / (float)N_;
    float mu  = sum[c] * invN;
    float var = sumsq[c] * invN - mu * mu;
    float v = (h[idx] - mu) * rsqrtf(var + EPSF) * g[c] + b[c];
    h[idx] = v > 0.f ? v : 0.f;
}

// ---------------- SAGE aggregate (mean) ----------------
__global__ void k_sage_agg(const float* __restrict__ h1, const int* __restrict__ rows,
                           const int* __restrict__ csr, float* __restrict__ agg) {
    int i = blockIdx.x * 4 + (threadIdx.x >> 6);
    int c = threadIdx.x & 63;
    int e0 = rows[i], e1 = rows[i+1];
    float s = 0.f;
    for (int e = e0; e < e1; ++e) s += h1[(size_t)csr[e]*64 + c];
    agg[(size_t)i*64 + c] = s / fmaxf((float)(e1 - e0), 1.0f);
}

// ---------------- generic tiled SGEMM: C[n,m] (+)= A[n,k] B[k,m] ----------------
__global__ __launch_bounds__(256) void k_gemm(const float* __restrict__ A,
                                              const float* __restrict__ B,
                                              const float* __restrict__ bias,
                                              float* __restrict__ C,
                                              int K, int M, int accum) {
    __shared__ float As[16][68];
    __shared__ float Bs[16][68];
    int tid = threadIdx.x;
    int tx = tid & 15, ty = tid >> 4;
    int row0 = blockIdx.y * 64, col0 = blockIdx.x * 64;
    float acc[4][4];
#pragma unroll
    for (int i = 0; i < 4; ++i)
#pragma unroll
        for (int j = 0; j < 4; ++j) acc[i][j] = 0.f;
    int lka = tid & 15, lra = tid >> 4;
    int lcb = tid & 63, lkb = tid >> 6;
    for (int k0 = 0; k0 < K; k0 += 16) {
#pragma unroll
        for (int it = 0; it < 4; ++it)
            As[lka][lra + it*16] = A[(size_t)(row0 + lra + it*16)*K + k0 + lka];
#pragma unroll
        for (int it = 0; it < 4; ++it)
            Bs[lkb + it*4][lcb] = B[(size_t)(k0 + lkb + it*4)*M + col0 + lcb];
        __syncthreads();
#pragma unroll
        for (int k = 0; k < 16; ++k) {
            float a0 = As[k][ty*4+0], a1 = As[k][ty*4+1],
                  a2 = As[k][ty*4+2], a3 = As[k][ty*4+3];
            float b0 = Bs[k][tx*4+0], b1 = Bs[k][tx*4+1],
                  b2 = Bs[k][tx*4+2], b3 = Bs[k][tx*4+3];
            acc[0][0] += a0*b0; acc[0][1] += a0*b1; acc[0][2] += a0*b2; acc[0][3] += a0*b3;
            acc[1][0] += a1*b0; acc[1][1] += a1*b1; acc[1][2] += a1*b2; acc[1][3] += a1*b3;
            acc[2][0] += a2*b0; acc[2][1] += a2*b1; acc[2][2] += a2*b2; acc[2][3] += a2*b3;
            acc[3][0] += a3*b0; acc[3][1] += a3*b1; acc[3][2] += a3*b2; acc[3][3] += a3*b3;
        }
        __syncthreads();
    }
#pragma unroll
    for (int i = 0; i < 4; ++i) {
        int r = row0 + ty*4 + i;
#pragma unroll
        for (int j = 0; j < 4; ++j) {
            int c = col0 + tx*4 + j;
            size_t idx = (size_t)r*M + c;
            float v = acc[i][j];
            if (bias)  v += bias[c];
            if (accum) v += C[idx];
            C[idx] = v;
        }
    }
}

// ---------------- GAT ----------------
__global__ __launch_bounds__(256) void k_gat_attn(const float* __restrict__ hg,
                                                  const float* __restrict__ asrc,
                                                  const float* __restrict__ adst,
                                                  float* __restrict__ es,
                                                  float* __restrict__ ed) {
    __shared__ float red[256];
    int i = blockIdx.x, t = threadIdx.x;
    for (int h = 0; h < 4; ++h) {
        float hv = hg[(size_t)i*1024 + h*256 + t];
        float pe = hv * asrc[h*256 + t];
        red[t] = pe; __syncthreads();
        for (int s = 128; s > 0; s >>= 1) { if (t < s) red[t] += red[t+s]; __syncthreads(); }
        if (t == 0) es[i*4 + h] = red[0];
        __syncthreads();
        float pd = hv * adst[h*256 + t];
        red[t] = pd; __syncthreads();
        for (int s = 128; s > 0; s >>= 1) { if (t < s) red[t] += red[t+s]; __syncthreads(); }
        if (t == 0) ed[i*4 + h] = red[0];
        __syncthreads();
    }
}

#define GCHUNK 1024
__global__ __launch_bounds__(256) void k_gat_agg(const float* __restrict__ hg,
                                                 const float* __restrict__ es,
                                                 const float* __restrict__ ed,
                                                 const int* __restrict__ rows,
                                                 const int* __restrict__ csr,
                                                 const float* __restrict__ gbias,
                                                 float* __restrict__ out) {
    __shared__ float se[GCHUNK * 4];
    __shared__ int ssrc[GCHUNK];
    int i = blockIdx.x, t = threadIdx.x;
    float edv[4], m[4], z[4], acc[4];
#pragma unroll
    for (int h = 0; h < 4; ++h) edv[h] = ed[i*4 + h];
#pragma unroll
    for (int h = 0; h < 4; ++h) {                 // self-loop
        float e = es[i*4 + h] + edv[h];
        e = e >= 0.f ? e : 0.2f * e;
        m[h] = e; z[h] = 1.f;
        acc[h] = hg[(size_t)i*1024 + h*256 + t];
    }
    int e0 = rows[i], e1 = rows[i+1];
    for (int c0 = e0; c0 < e1; c0 += GCHUNK) {
        int cn = min(GCHUNK, e1 - c0);
        for (int j = t; j < cn; j += 256) {
            int s = csr[c0 + j];
            ssrc[j] = s;
#pragma unroll
            for (int h = 0; h < 4; ++h) {
                float e = es[s*4 + h] + edv[h];
                se[j*4 + h] = e >= 0.f ? e : 0.2f * e;
            }
        }
        __syncthreads();
        float nm[4] = {m[0], m[1], m[2], m[3]};
        for (int j = 0; j < cn; ++j) {
#pragma unroll
            for (int h = 0; h < 4; ++h) nm[h] = fmaxf(nm[h], se[j*4 + h]);
        }
#pragma unroll
        for (int h = 0; h < 4; ++h) {
            float sc = __expf(m[h] - nm[h]);
            z[h] *= sc; acc[h] *= sc; m[h] = nm[h];
        }
        for (int j = 0; j < cn; ++j) {
            int s = ssrc[j];
#pragma unroll
            for (int h = 0; h < 4; ++h) {
                float a = __expf(se[j*4 + h] - m[h]);
                z[h] += a;
                acc[h] += a * hg[(size_t)s*1024 + h*256 + t];
            }
        }
        __syncthreads();
    }
    float o = 0.25f * (acc[0]/z[0] + acc[1]/z[1] + acc[2]/z[2] + acc[3]/z[3]);
    out[(size_t)i*256 + t] = o + gbias[t];
}

// ---------------- layer 4: GCN(256->512) aggregate ----------------
__global__ __launch_bounds__(256) void k_gcn4_agg(const float* __restrict__ h3,
                                                  const float* __restrict__ dis,
                                                  const int* __restrict__ rows,
                                                  const int* __restrict__ csr,
                                                  float* __restrict__ xa) {
    int i = blockIdx.x, t = threadIdx.x;
    float di = dis[i];
    float a = h3[(size_t)i*256 + t] * di * di;
    int e0 = rows[i], e1 = rows[i+1];
    for (int e = e0; e < e1; ++e) {
        int s = csr[e];
        a += h3[(size_t)s*256 + t] * (dis[s] * di);
    }
    xa[(size_t)i*256 + t] = a;
}

// ---------------- pooling ----------------
__global__ void k_pool(const float* __restrict__ h4, const int* __restrict__ gb,
                       float* __restrict__ pooled) {
    int g = blockIdx.y;
    int t = threadIdx.x;
    int r0g = gb[g], r1g = gb[g+1];
    int n = r1g - r0g;
    if (n <= 0) return;
    int per = (n + 15) >> 4;
    int r0 = r0g + blockIdx.x * per;
    int r1 = min(r0 + per, r1g);
    if (r0 >= r1) return;
    float s0=0.f, s1=0.f, m0=0.f, m1=0.f;   // h4 >= 0 post-ReLU: max init 0 valid
    for (int r = r0; r < r1; ++r) {
        float v = h4[(size_t)r*512 + t];       s0 += v; m0 = fmaxf(m0, v);
        float w = h4[(size_t)r*512 + 256 + t]; s1 += w; m1 = fmaxf(m1, w);
    }
    atomicAdd(&pooled[g*1024 + t], s0);
    atomicAdd(&pooled[g*1024 + 256 + t], s1);
    atomicMax((int*)&pooled[g*1024 + 512 + t],  __float_as_int(m0));
    atomicMax((int*)&pooled[g*1024 + 768 + t],  __float_as_int(m1));
}

__global__ void k_pool_fin(float* __restrict__ pooled, const int* __restrict__ gb) {
    int g = blockIdx.x, t = threadIdx.x;    // 512 threads
    int cnt = gb[g+1] - gb[g];
    pooled[g*1024 + t] *= 1.0f / fmaxf((float)cnt, 1.0f);
}

// ---------------- FC ----------------
__global__ __launch_bounds__(256) void k_fc(const float* __restrict__ pooled,
                                            const float* __restrict__ w,
                                            const float* __restrict__ b,
                                            float* __restrict__ out) {
    __shared__ float pr[1024];
    int g = blockIdx.y;
    int m = blockIdx.x * 256 + threadIdx.x;
    for (int k = threadIdx.x; k < 1024; k += 256) pr[k] = pooled[g*1024 + k];
    __syncthreads();
    float acc = b[m];
#pragma unroll 4
    for (int k = 0; k < 1024; ++k) acc += pr[k] * w[k*1024 + m];
    out[g*1024 + m] = acc;
}

// ---------------- host ----------------
extern "C" void kernel_launch(void* const* d_in, const int* in_sizes, int n_in,
                              void* d_out, int out_size, void* d_ws, size_t ws_size,
                              hipStream_t stream) {
    (void)in_sizes; (void)n_in; (void)out_size; (void)ws_size;
    const float* x       = (const float*)d_in[0];
    const int*   ei      = (const int*)d_in[1];
    const int*   batch   = (const int*)d_in[2];
    const float* gcn1_w  = (const float*)d_in[3];
    const float* gcn1_b  = (const float*)d_in[4];
    const float* sage_wl = (const float*)d_in[5];
    const float* sage_wr = (const float*)d_in[6];
    const float* sage_b  = (const float*)d_in[7];
    const float* gat_w   = (const float*)d_in[8];
    const float* gat_as  = (const float*)d_in[9];
    const float* gat_ad  = (const float*)d_in[10];
    const float* gat_b   = (const float*)d_in[11];
    const float* gcn4_w  = (const float*)d_in[12];
    const float* gcn4_b  = (const float*)d_in[13];
    const float* bn1_g   = (const float*)d_in[14];
    const float* bn1_b   = (const float*)d_in[15];
    const float* bn2_g   = (const float*)d_in[16];
    const float* bn2_b   = (const float*)d_in[17];
    const float* bn3_g   = (const float*)d_in[18];
    const float* bn3_b   = (const float*)d_in[19];
    const float* bn4_g   = (const float*)d_in[20];
    const float* bn4_b   = (const float*)d_in[21];
    const float* fc_w    = (const float*)d_in[22];
    const float* fc_b    = (const float*)d_in[23];
    float* out = (float*)d_out;

    char* w8 = (char*)d_ws;
    int*   indeg  = (int*)(w8 + OFF_INDEG);
    int*   rows   = (int*)(w8 + OFF_ROWS);
    int*   cursor = (int*)(w8 + OFF_CURSOR);
    int*   csr    = (int*)(w8 + OFF_CSR);
    float* dis    = (float*)(w8 + OFF_DIS);
    float* es     = (float*)(w8 + OFF_ES);
    float* ed     = (float*)(w8 + OFF_ED);
    float* bns    = (float*)(w8 + OFF_BNS);
    float* bnq    = (float*)(w8 + OFF_BNQ);
    int*   gb     = (int*)(w8 + OFF_GB);
    float* pooled = (float*)(w8 + OFF_POOL);
    float* xa1    = (float*)(w8 + OFF_XA1);
    float* h1     = (float*)(w8 + OFF_H1);
    float* agg    = (float*)(w8 + OFF_AGG);
    float* h2     = (float*)(w8 + OFF_H2);
    float* h3     = (float*)(w8 + OFF_H3);
    float* hgat   = (float*)(w8 + OFF_HGAT);
    float* xa4    = (float*)(w8 + OFF_XA4);
    float* h4     = (float*)(w8 + OFF_H4);

    const int* srcE = ei;        // edge_index[0,:]
    const int* dstE = ei + E_;   // edge_index[1,:]

    const int BNB = 512;         // bn-stats blocks (was 32: 1.3% occupancy, 145us/dispatch)
    const int BNR = N_ / BNB;    // rows per block

    // ---- graph structure ----
    hipMemsetAsync(indeg, 0, N_ * sizeof(int), stream);
    k_indeg<<<E_/256, 256, 0, stream>>>(dstE, indeg);
    k_dis<<<N_/256, 256, 0, stream>>>(indeg, dis);
    k_scan<<<1, 1024, 0, stream>>>(indeg, rows);
    hipMemcpyAsync(cursor, rows, N_ * sizeof(int), hipMemcpyDeviceToDevice, stream);
    k_fill<<<E_/256, 256, 0, stream>>>(srcE, dstE, cursor, csr);
    k_gbounds<<<1, 64, 0, stream>>>(batch, gb);

    // ---- layer 1: GCN 5->64, BN, ReLU ----
    k_gcn1_agg<<<N_/256, 256, 0, stream>>>(x, dis, rows, csr, xa1);
    k_mm5<<<(N_*64)/256, 256, 0, stream>>>(xa1, gcn1_w, gcn1_b, h1);
    hipMemsetAsync(bns, 0, 4096, stream);
    k_bn_stats<<<BNB, 256, 0, stream>>>(h1, bns, bnq, 64, BNR);
    k_bn_apply<<<(N_*64)/256, 256, 0, stream>>>(h1, bns, bnq, bn1_g, bn1_b, 64, N_*64);

    // ---- layer 2: SAGE 64->128, BN, ReLU ----
    k_sage_agg<<<N_/4, 256, 0, stream>>>(h1, rows, csr, agg);
    {
        dim3 grid(128/64, N_/64);
        k_gemm<<<grid, 256, 0, stream>>>(agg, sage_wl, nullptr, h2, 64, 128, 0);
        k_gemm<<<grid, 256, 0, stream>>>(h1, sage_wr, sage_b, h2, 64, 128, 1);
    }
    hipMemsetAsync(bns, 0, 4096, stream);
    k_bn_stats<<<BNB, 256, 0, stream>>>(h2, bns, bnq, 128, BNR);
    k_bn_apply<<<(N_*128)/256, 256, 0, stream>>>(h2, bns, bnq, bn2_g, bn2_b, 128, N_*128);

    // ---- layer 3: GAT 128->4x256 (head-mean -> 256), BN, ReLU ----
    {
        dim3 grid(1024/64, N_/64);
        k_gemm<<<grid, 256, 0, stream>>>(h2, gat_w, nullptr, hgat, 128, 1024, 0);
    }
    k_gat_attn<<<N_, 256, 0, stream>>>(hgat, gat_as, gat_ad, es, ed);
    k_gat_agg<<<N_, 256, 0, stream>>>(hgat, es, ed, rows, csr, gat_b, h3);
    hipMemsetAsync(bns, 0, 4096, stream);
    k_bn_stats<<<BNB, 256, 0, stream>>>(h3, bns, bnq, 256, BNR);
    k_bn_apply<<<(N_*256)/256, 256, 0, stream>>>(h3, bns, bnq, bn3_g, bn3_b, 256, N_*256);

    // ---- layer 4: GCN 256->512, BN, ReLU ----
    k_gcn4_agg<<<N_, 256, 0, stream>>>(h3, dis, rows, csr, xa4);
    {
        dim3 grid(512/64, N_/64);
        k_gemm<<<grid, 256, 0, stream>>>(xa4, gcn4_w, gcn4_b, h4, 256, 512, 0);
    }
    hipMemsetAsync(bns, 0, 4096, stream);
    k_bn_stats<<<BNB, 256, 0, stream>>>(h4, bns, bnq, 512, BNR);
    k_bn_apply<<<(N_*512)/256, 256, 0, stream>>>(h4, bns, bnq, bn4_g, bn4_b, 512, N_*512);

    // ---- pooling (mean | max) -> [32,1024] ----
    hipMemsetAsync(pooled, 0, 32 * 1024 * sizeof(float), stream);
    {
        dim3 grid(16, G_);
        k_pool<<<grid, 256, 0, stream>>>(h4, gb, pooled);
    }
    k_pool_fin<<<G_, 512, 0, stream>>>(pooled, gb);

    // ---- FC 1024->1024 ----
    {
        dim3 grid(1024/256, G_);
        k_fc<<<grid, 256, 0, stream>>>(pooled, fc_w, fc_b, out);
    }
}

// Round 3
// 661.673 us; speedup vs baseline: 1.5292x; 1.0813x over previous
//
#include <hip/hip_runtime.h>

#define N_ 16384
#define E_ 131072
#define G_ 32
#define EPSF 1e-5f

// ---------------- workspace layout (bytes) ----------------
static const size_t OFF_INDEG = 0;          // int[N]        65536
static const size_t OFF_ROWS  = 65536;      // int[N+1]      (pad)
static const size_t OFF_CURSOR= 131584;     // int[N]
static const size_t OFF_CSR   = 197120;     // int[E]        524288
static const size_t OFF_DIS   = 721408;     // float[N]
static const size_t OFF_ES    = 786944;     // float[4N]
static const size_t OFF_ED    = 1049088;    // float[4N]
static const size_t OFF_BNS   = 1311232;    // float[512]
static const size_t OFF_BNQ   = 1313280;    // float[512]
static const size_t OFF_GB    = 1315328;    // int[33]
static const size_t OFF_POOL  = 1315584;    // float[32*1024]
static const size_t OFF_XA1   = 1446656;    // float[5N]
static const size_t OFF_H1    = 1774336;    // float[64N]   4 MB
static const size_t OFF_AGG   = 5968640;    // float[64N]   4 MB
static const size_t OFF_H2    = 10162944;   // float[128N]  8 MB
static const size_t OFF_H3    = 18551552;   // float[256N]  16 MB
static const size_t OFF_HGAT  = 35328768;   // float[1024N] 64 MB
static const size_t OFF_XA4   = OFF_HGAT;            // reuse (hgat dead)
static const size_t OFF_H4    = OFF_HGAT + 16777216; // reuse
// total ≈ 97.7 MB

// ---------------- graph structure ----------------
__global__ void k_indeg(const int* __restrict__ dst, int* __restrict__ indeg) {
    int e = blockIdx.x * 256 + threadIdx.x;
    if (e < E_) atomicAdd(&indeg[dst[e]], 1);
}

__global__ void k_dis(const int* __restrict__ indeg, float* __restrict__ dis) {
    int i = blockIdx.x * 256 + threadIdx.x;
    if (i < N_) dis[i] = rsqrtf((float)indeg[i] + 1.0f);
}

__global__ __launch_bounds__(1024) void k_scan(const int* __restrict__ indeg,
                                               int* __restrict__ rows) {
    __shared__ int part[1024];
    int t = threadIdx.x;
    int base = t * 16;
    int local[16];
    int s = 0;
#pragma unroll
    for (int i = 0; i < 16; ++i) { local[i] = indeg[base + i]; s += local[i]; }
    part[t] = s;
    __syncthreads();
    for (int off = 1; off < 1024; off <<= 1) {
        int v = (t >= off) ? part[t - off] : 0;
        __syncthreads();
        part[t] += v;
        __syncthreads();
    }
    int run = (t == 0) ? 0 : part[t - 1];
#pragma unroll
    for (int i = 0; i < 16; ++i) { rows[base + i] = run; run += local[i]; }
    if (t == 1023) rows[N_] = run;
}

__global__ void k_fill(const int* __restrict__ src, const int* __restrict__ dst,
                       int* __restrict__ cursor, int* __restrict__ csr) {
    int e = blockIdx.x * 256 + threadIdx.x;
    if (e < E_) {
        int p = atomicAdd(&cursor[dst[e]], 1);
        csr[p] = src[e];
    }
}

__global__ void k_gbounds(const int* __restrict__ batch, int* __restrict__ gb) {
    int g = threadIdx.x;
    if (g > G_) return;
    if (g == G_) { gb[G_] = N_; return; }
    int lo = 0, hi = N_;
    while (lo < hi) { int mid = (lo + hi) >> 1; if (batch[mid] < g) lo = mid + 1; else hi = mid; }
    gb[g] = lo;
}

// ---------------- layer 1: GCN(5->64) ----------------
__global__ void k_gcn1_agg(const float* __restrict__ x, const float* __restrict__ dis,
                           const int* __restrict__ rows, const int* __restrict__ csr,
                           float* __restrict__ xa) {
    int i = blockIdx.x * 256 + threadIdx.x;
    if (i >= N_) return;
    float di = dis[i];
    float a0 = x[i*5+0]*di*di, a1 = x[i*5+1]*di*di, a2 = x[i*5+2]*di*di,
          a3 = x[i*5+3]*di*di, a4 = x[i*5+4]*di*di;
    int e0 = rows[i], e1 = rows[i+1];
    for (int e = e0; e < e1; ++e) {
        int s = csr[e];
        float w = dis[s] * di;
        a0 += x[s*5+0]*w; a1 += x[s*5+1]*w; a2 += x[s*5+2]*w;
        a3 += x[s*5+3]*w; a4 += x[s*5+4]*w;
    }
    xa[i*5+0]=a0; xa[i*5+1]=a1; xa[i*5+2]=a2; xa[i*5+3]=a3; xa[i*5+4]=a4;
}

__global__ void k_mm5(const float* __restrict__ xa, const float* __restrict__ w,
                      const float* __restrict__ b, float* __restrict__ out) {
    int idx = blockIdx.x * 256 + threadIdx.x;   // N*64
    int n = idx >> 6, m = idx & 63;
    float s = b[m];
#pragma unroll
    for (int k = 0; k < 5; ++k) s += xa[n*5+k] * w[k*64+m];
    out[idx] = s;
}

// ---------------- batchnorm ----------------
// grid = 512 blocks (rowsPerBlock = 32): round-1 profile showed 32-block
// launch at 1.3% occupancy / 116 GB/s was ~half of total runtime.
__global__ void k_bn_stats(const float* __restrict__ x, float* __restrict__ sum,
                           float* __restrict__ sumsq, int C, int rowsPerBlock) {
    int t = threadIdx.x;
    size_t base = (size_t)blockIdx.x * rowsPerBlock * C;
    size_t end  = base + (size_t)rowsPerBlock * C;
    if (C == 512) {
        float s0=0,q0=0,s1=0,q1=0;
        for (size_t f = base + t; f < end; f += 512) {
            float v = x[f];     s0 += v; q0 += v*v;
            float w = x[f+256]; s1 += w; q1 += w*w;
        }
        atomicAdd(&sum[t], s0);      atomicAdd(&sumsq[t], q0);
        atomicAdd(&sum[t+256], s1);  atomicAdd(&sumsq[t+256], q1);
    } else {
        float s0=0,q0=0;
        for (size_t f = base + t; f < end; f += 256) {
            float v = x[f]; s0 += v; q0 += v*v;
        }
        __shared__ float ls[256], lq[256];
        ls[t]=s0; lq[t]=q0;
        __syncthreads();
        if (t < C) {
            for (int j = t + C; j < 256; j += C) { s0 += ls[j]; q0 += lq[j]; }
            atomicAdd(&sum[t], s0); atomicAdd(&sumsq[t], q0);
        }
    }
}

__global__ void k_bn_apply(float* __restrict__ h, const float* __restrict__ sum,
                           const float* __restrict__ sumsq, const float* __restrict__ g,
                           const float* __restrict__ b, int C, int total) {
    int idx = blockIdx.x * 256 + threadIdx.x;
    if (idx >= total) return;
    int c = idx & (C - 1);
    const float invN = 1.0f / (float)N_;
    float mu  = sum[c] * invN;
    float var = sumsq[c] * invN - mu * mu;
    float v = (h[idx] - mu) * rsqrtf(var + EPSF) * g[c] + b[c];
    h[idx] = v > 0.f ? v : 0.f;
}

// ---------------- SAGE aggregate (mean) ----------------
__global__ void k_sage_agg(const float* __restrict__ h1, const int* __restrict__ rows,
                           const int* __restrict__ csr, float* __restrict__ agg) {
    int i = blockIdx.x * 4 + (threadIdx.x >> 6);
    int c = threadIdx.x & 63;
    int e0 = rows[i], e1 = rows[i+1];
    float s = 0.f;
    for (int e = e0; e < e1; ++e) s += h1[(size_t)csr[e]*64 + c];
    agg[(size_t)i*64 + c] = s / fmaxf((float)(e1 - e0), 1.0f);
}

// ---------------- generic tiled SGEMM: C[n,m] (+)= A[n,k] B[k,m] ----------------
__global__ __launch_bounds__(256) void k_gemm(const float* __restrict__ A,
                                              const float* __restrict__ B,
                                              const float* __restrict__ bias,
                                              float* __restrict__ C,
                                              int K, int M, int accum) {
    __shared__ float As[16][68];
    __shared__ float Bs[16][68];
    int tid = threadIdx.x;
    int tx = tid & 15, ty = tid >> 4;
    int row0 = blockIdx.y * 64, col0 = blockIdx.x * 64;
    float acc[4][4];
#pragma unroll
    for (int i = 0; i < 4; ++i)
#pragma unroll
        for (int j = 0; j < 4; ++j) acc[i][j] = 0.f;
    int lka = tid & 15, lra = tid >> 4;
    int lcb = tid & 63, lkb = tid >> 6;
    for (int k0 = 0; k0 < K; k0 += 16) {
#pragma unroll
        for (int it = 0; it < 4; ++it)
            As[lka][lra + it*16] = A[(size_t)(row0 + lra + it*16)*K + k0 + lka];
#pragma unroll
        for (int it = 0; it < 4; ++it)
            Bs[lkb + it*4][lcb] = B[(size_t)(k0 + lkb + it*4)*M + col0 + lcb];
        __syncthreads();
#pragma unroll
        for (int k = 0; k < 16; ++k) {
            float a0 = As[k][ty*4+0], a1 = As[k][ty*4+1],
                  a2 = As[k][ty*4+2], a3 = As[k][ty*4+3];
            float b0 = Bs[k][tx*4+0], b1 = Bs[k][tx*4+1],
                  b2 = Bs[k][tx*4+2], b3 = Bs[k][tx*4+3];
            acc[0][0] += a0*b0; acc[0][1] += a0*b1; acc[0][2] += a0*b2; acc[0][3] += a0*b3;
            acc[1][0] += a1*b0; acc[1][1] += a1*b1; acc[1][2] += a1*b2; acc[1][3] += a1*b3;
            acc[2][0] += a2*b0; acc[2][1] += a2*b1; acc[2][2] += a2*b2; acc[2][3] += a2*b3;
            acc[3][0] += a3*b0; acc[3][1] += a3*b1; acc[3][2] += a3*b2; acc[3][3] += a3*b3;
        }
        __syncthreads();
    }
#pragma unroll
    for (int i = 0; i < 4; ++i) {
        int r = row0 + ty*4 + i;
#pragma unroll
        for (int j = 0; j < 4; ++j) {
            int c = col0 + tx*4 + j;
            size_t idx = (size_t)r*M + c;
            float v = acc[i][j];
            if (bias)  v += bias[c];
            if (accum) v += C[idx];
            C[idx] = v;
        }
    }
}

// ---------------- GAT ----------------
__global__ __launch_bounds__(256) void k_gat_attn(const float* __restrict__ hg,
                                                  const float* __restrict__ asrc,
                                                  const float* __restrict__ adst,
                                                  float* __restrict__ es,
                                                  float* __restrict__ ed) {
    __shared__ float red[256];
    int i = blockIdx.x, t = threadIdx.x;
    for (int h = 0; h < 4; ++h) {
        float hv = hg[(size_t)i*1024 + h*256 + t];
        float pe = hv * asrc[h*256 + t];
        red[t] = pe; __syncthreads();
        for (int s = 128; s > 0; s >>= 1) { if (t < s) red[t] += red[t+s]; __syncthreads(); }
        if (t == 0) es[i*4 + h] = red[0];
        __syncthreads();
        float pd = hv * adst[h*256 + t];
        red[t] = pd; __syncthreads();
        for (int s = 128; s > 0; s >>= 1) { if (t < s) red[t] += red[t+s]; __syncthreads(); }
        if (t == 0) ed[i*4 + h] = red[0];
        __syncthreads();
    }
}

#define GCHUNK 1024
__global__ __launch_bounds__(256) void k_gat_agg(const float* __restrict__ hg,
                                                 const float* __restrict__ es,
                                                 const float* __restrict__ ed,
                                                 const int* __restrict__ rows,
                                                 const int* __restrict__ csr,
                                                 const float* __restrict__ gbias,
                                                 float* __restrict__ out) {
    __shared__ float se[GCHUNK * 4];
    __shared__ int ssrc[GCHUNK];
    int i = blockIdx.x, t = threadIdx.x;
    float edv[4], m[4], z[4], acc[4];
#pragma unroll
    for (int h = 0; h < 4; ++h) edv[h] = ed[i*4 + h];
#pragma unroll
    for (int h = 0; h < 4; ++h) {                 // self-loop
        float e = es[i*4 + h] + edv[h];
        e = e >= 0.f ? e : 0.2f * e;
        m[h] = e; z[h] = 1.f;
        acc[h] = hg[(size_t)i*1024 + h*256 + t];
    }
    int e0 = rows[i], e1 = rows[i+1];
    for (int c0 = e0; c0 < e1; c0 += GCHUNK) {
        int cn = min(GCHUNK, e1 - c0);
        for (int j = t; j < cn; j += 256) {
            int s = csr[c0 + j];
            ssrc[j] = s;
#pragma unroll
            for (int h = 0; h < 4; ++h) {
                float e = es[s*4 + h] + edv[h];
                se[j*4 + h] = e >= 0.f ? e : 0.2f * e;
            }
        }
        __syncthreads();
        float nm[4] = {m[0], m[1], m[2], m[3]};
        for (int j = 0; j < cn; ++j) {
#pragma unroll
            for (int h = 0; h < 4; ++h) nm[h] = fmaxf(nm[h], se[j*4 + h]);
        }
#pragma unroll
        for (int h = 0; h < 4; ++h) {
            float sc = __expf(m[h] - nm[h]);
            z[h] *= sc; acc[h] *= sc; m[h] = nm[h];
        }
        for (int j = 0; j < cn; ++j) {
            int s = ssrc[j];
#pragma unroll
            for (int h = 0; h < 4; ++h) {
                float a = __expf(se[j*4 + h] - m[h]);
                z[h] += a;
                acc[h] += a * hg[(size_t)s*1024 + h*256 + t];
            }
        }
        __syncthreads();
    }
    float o = 0.25f * (acc[0]/z[0] + acc[1]/z[1] + acc[2]/z[2] + acc[3]/z[3]);
    out[(size_t)i*256 + t] = o + gbias[t];
}

// ---------------- layer 4: GCN(256->512) aggregate ----------------
__global__ __launch_bounds__(256) void k_gcn4_agg(const float* __restrict__ h3,
                                                  const float* __restrict__ dis,
                                                  const int* __restrict__ rows,
                                                  const int* __restrict__ csr,
                                                  float* __restrict__ xa) {
    int i = blockIdx.x, t = threadIdx.x;
    float di = dis[i];
    float a = h3[(size_t)i*256 + t] * di * di;
    int e0 = rows[i], e1 = rows[i+1];
    for (int e = e0; e < e1; ++e) {
        int s = csr[e];
        a += h3[(size_t)s*256 + t] * (dis[s] * di);
    }
    xa[(size_t)i*256 + t] = a;
}

// ---------------- pooling ----------------
__global__ void k_pool(const float* __restrict__ h4, const int* __restrict__ gb,
                       float* __restrict__ pooled) {
    int g = blockIdx.y;
    int t = threadIdx.x;
    int r0g = gb[g], r1g = gb[g+1];
    int n = r1g - r0g;
    if (n <= 0) return;
    int per = (n + 15) >> 4;
    int r0 = r0g + blockIdx.x * per;
    int r1 = min(r0 + per, r1g);
    if (r0 >= r1) return;
    float s0=0.f, s1=0.f, m0=0.f, m1=0.f;   // h4 >= 0 post-ReLU: max init 0 valid
    for (int r = r0; r < r1; ++r) {
        float v = h4[(size_t)r*512 + t];       s0 += v; m0 = fmaxf(m0, v);
        float w = h4[(size_t)r*512 + 256 + t]; s1 += w; m1 = fmaxf(m1, w);
    }
    atomicAdd(&pooled[g*1024 + t], s0);
    atomicAdd(&pooled[g*1024 + 256 + t], s1);
    atomicMax((int*)&pooled[g*1024 + 512 + t],  __float_as_int(m0));
    atomicMax((int*)&pooled[g*1024 + 768 + t],  __float_as_int(m1));
}

__global__ void k_pool_fin(float* __restrict__ pooled, const int* __restrict__ gb) {
    int g = blockIdx.x, t = threadIdx.x;    // 512 threads
    int cnt = gb[g+1] - gb[g];
    pooled[g*1024 + t] *= 1.0f / fmaxf((float)cnt, 1.0f);
}

// ---------------- FC (v2: K-split, float4, atomic reduce) ----------------
// Round-2 profile: old k_fc was 100us @ 5.7% occupancy, 46 GB/s — 128 blocks
// latency-bound on a 1024-deep serial load chain. v2: grid (32 g x 16 kz) =
// 512 blocks; each thread owns 4 outputs (float4 weight loads), 64-iter
// K-chunk; partials combined with atomicAdd (16 contenders/address).
#define FCKZ 16
#define FCKC (1024 / FCKZ)   // 64

__global__ void k_fc_init(const float* __restrict__ b, float* __restrict__ out) {
    int i = blockIdx.x * 256 + threadIdx.x;   // 32*1024
    out[i] = b[i & 1023];
}

__global__ __launch_bounds__(256) void k_fc2(const float* __restrict__ pooled,
                                             const float* __restrict__ w,
                                             float* __restrict__ out) {
    __shared__ float pr[FCKC];
    int g = blockIdx.x;
    int z = blockIdx.y;
    int t = threadIdx.x;
    int k0 = z * FCKC;
    if (t < FCKC) pr[t] = pooled[g * 1024 + k0 + t];
    __syncthreads();
    int m0 = t * 4;
    float ax = 0.f, ay = 0.f, az = 0.f, aw = 0.f;
#pragma unroll 8
    for (int k = 0; k < FCKC; ++k) {
        const float4 wv = *(const float4*)&w[(size_t)(k0 + k) * 1024 + m0];
        float p = pr[k];
        ax += p * wv.x; ay += p * wv.y; az += p * wv.z; aw += p * wv.w;
    }
    atomicAdd(&out[g * 1024 + m0 + 0], ax);
    atomicAdd(&out[g * 1024 + m0 + 1], ay);
    atomicAdd(&out[g * 1024 + m0 + 2], az);
    atomicAdd(&out[g * 1024 + m0 + 3], aw);
}

// ---------------- host ----------------
extern "C" void kernel_launch(void* const* d_in, const int* in_sizes, int n_in,
                              void* d_out, int out_size, void* d_ws, size_t ws_size,
                              hipStream_t stream) {
    (void)in_sizes; (void)n_in; (void)out_size; (void)ws_size;
    const float* x       = (const float*)d_in[0];
    const int*   ei      = (const int*)d_in[1];
    const int*   batch   = (const int*)d_in[2];
    const float* gcn1_w  = (const float*)d_in[3];
    const float* gcn1_b  = (const float*)d_in[4];
    const float* sage_wl = (const float*)d_in[5];
    const float* sage_wr = (const float*)d_in[6];
    const float* sage_b  = (const float*)d_in[7];
    const float* gat_w   = (const float*)d_in[8];
    const float* gat_as  = (const float*)d_in[9];
    const float* gat_ad  = (const float*)d_in[10];
    const float* gat_b   = (const float*)d_in[11];
    const float* gcn4_w  = (const float*)d_in[12];
    const float* gcn4_b  = (const float*)d_in[13];
    const float* bn1_g   = (const float*)d_in[14];
    const float* bn1_b   = (const float*)d_in[15];
    const float* bn2_g   = (const float*)d_in[16];
    const float* bn2_b   = (const float*)d_in[17];
    const float* bn3_g   = (const float*)d_in[18];
    const float* bn3_b   = (const float*)d_in[19];
    const float* bn4_g   = (const float*)d_in[20];
    const float* bn4_b   = (const float*)d_in[21];
    const float* fc_w    = (const float*)d_in[22];
    const float* fc_b    = (const float*)d_in[23];
    float* out = (float*)d_out;

    char* w8 = (char*)d_ws;
    int*   indeg  = (int*)(w8 + OFF_INDEG);
    int*   rows   = (int*)(w8 + OFF_ROWS);
    int*   cursor = (int*)(w8 + OFF_CURSOR);
    int*   csr    = (int*)(w8 + OFF_CSR);
    float* dis    = (float*)(w8 + OFF_DIS);
    float* es     = (float*)(w8 + OFF_ES);
    float* ed     = (float*)(w8 + OFF_ED);
    float* bns    = (float*)(w8 + OFF_BNS);
    float* bnq    = (float*)(w8 + OFF_BNQ);
    int*   gb     = (int*)(w8 + OFF_GB);
    float* pooled = (float*)(w8 + OFF_POOL);
    float* xa1    = (float*)(w8 + OFF_XA1);
    float* h1     = (float*)(w8 + OFF_H1);
    float* agg    = (float*)(w8 + OFF_AGG);
    float* h2     = (float*)(w8 + OFF_H2);
    float* h3     = (float*)(w8 + OFF_H3);
    float* hgat   = (float*)(w8 + OFF_HGAT);
    float* xa4    = (float*)(w8 + OFF_XA4);
    float* h4     = (float*)(w8 + OFF_H4);

    const int* srcE = ei;        // edge_index[0,:]
    const int* dstE = ei + E_;   // edge_index[1,:]

    const int BNB = 512;         // bn-stats blocks (was 32: 1.3% occupancy, 145us/dispatch)
    const int BNR = N_ / BNB;    // rows per block

    // ---- graph structure ----
    hipMemsetAsync(indeg, 0, N_ * sizeof(int), stream);
    k_indeg<<<E_/256, 256, 0, stream>>>(dstE, indeg);
    k_dis<<<N_/256, 256, 0, stream>>>(indeg, dis);
    k_scan<<<1, 1024, 0, stream>>>(indeg, rows);
    hipMemcpyAsync(cursor, rows, N_ * sizeof(int), hipMemcpyDeviceToDevice, stream);
    k_fill<<<E_/256, 256, 0, stream>>>(srcE, dstE, cursor, csr);
    k_gbounds<<<1, 64, 0, stream>>>(batch, gb);

    // ---- layer 1: GCN 5->64, BN, ReLU ----
    k_gcn1_agg<<<N_/256, 256, 0, stream>>>(x, dis, rows, csr, xa1);
    k_mm5<<<(N_*64)/256, 256, 0, stream>>>(xa1, gcn1_w, gcn1_b, h1);
    hipMemsetAsync(bns, 0, 4096, stream);
    k_bn_stats<<<BNB, 256, 0, stream>>>(h1, bns, bnq, 64, BNR);
    k_bn_apply<<<(N_*64)/256, 256, 0, stream>>>(h1, bns, bnq, bn1_g, bn1_b, 64, N_*64);

    // ---- layer 2: SAGE 64->128, BN, ReLU ----
    k_sage_agg<<<N_/4, 256, 0, stream>>>(h1, rows, csr, agg);
    {
        dim3 grid(128/64, N_/64);
        k_gemm<<<grid, 256, 0, stream>>>(agg, sage_wl, nullptr, h2, 64, 128, 0);
        k_gemm<<<grid, 256, 0, stream>>>(h1, sage_wr, sage_b, h2, 64, 128, 1);
    }
    hipMemsetAsync(bns, 0, 4096, stream);
    k_bn_stats<<<BNB, 256, 0, stream>>>(h2, bns, bnq, 128, BNR);
    k_bn_apply<<<(N_*128)/256, 256, 0, stream>>>(h2, bns, bnq, bn2_g, bn2_b, 128, N_*128);

    // ---- layer 3: GAT 128->4x256 (head-mean -> 256), BN, ReLU ----
    {
        dim3 grid(1024/64, N_/64);
        k_gemm<<<grid, 256, 0, stream>>>(h2, gat_w, nullptr, hgat, 128, 1024, 0);
    }
    k_gat_attn<<<N_, 256, 0, stream>>>(hgat, gat_as, gat_ad, es, ed);
    k_gat_agg<<<N_, 256, 0, stream>>>(hgat, es, ed, rows, csr, gat_b, h3);
    hipMemsetAsync(bns, 0, 4096, stream);
    k_bn_stats<<<BNB, 256, 0, stream>>>(h3, bns, bnq, 256, BNR);
    k_bn_apply<<<(N_*256)/256, 256, 0, stream>>>(h3, bns, bnq, bn3_g, bn3_b, 256, N_*256);

    // ---- layer 4: GCN 256->512, BN, ReLU ----
    k_gcn4_agg<<<N_, 256, 0, stream>>>(h3, dis, rows, csr, xa4);
    {
        dim3 grid(512/64, N_/64);
        k_gemm<<<grid, 256, 0, stream>>>(xa4, gcn4_w, gcn4_b, h4, 256, 512, 0);
    }
    hipMemsetAsync(bns, 0, 4096, stream);
    k_bn_stats<<<BNB, 256, 0, stream>>>(h4, bns, bnq, 512, BNR);
    k_bn_apply<<<(N_*512)/256, 256, 0, stream>>>(h4, bns, bnq, bn4_g, bn4_b, 512, N_*512);

    // ---- pooling (mean | max) -> [32,1024] ----
    hipMemsetAsync(pooled, 0, 32 * 1024 * sizeof(float), stream);
    {
        dim3 grid(16, G_);
        k_pool<<<grid, 256, 0, stream>>>(h4, gb, pooled);
    }
    k_pool_fin<<<G_, 512, 0, stream>>>(pooled, gb);

    // ---- FC 1024->1024 (v2) ----
    k_fc_init<<<(G_*1024)/256, 256, 0, stream>>>(fc_b, out);
    {
        dim3 grid(G_, FCKZ);
        k_fc2<<<grid, 256, 0, stream>>>(pooled, fc_w, out);
    }
}

// Round 4
// 574.699 us; speedup vs baseline: 1.7606x; 1.1513x over previous
//
#include <hip/hip_runtime.h>

#define N_ 16384
#define E_ 131072
#define G_ 32
#define EPSF 1e-5f

typedef unsigned short bf16u;

__device__ __forceinline__ bf16u f2bf(float v) {
    union { float f; unsigned u; } x; x.f = v;
    unsigned r = x.u + 0x7FFF + ((x.u >> 16) & 1);   // RNE
    return (bf16u)(r >> 16);
}
__device__ __forceinline__ float bf2f(bf16u u) {
    union { unsigned u; float f; } x; x.u = (unsigned)u << 16;
    return x.f;
}

// ---------------- workspace layout (bytes) ----------------
static const size_t OFF_INDEG = 0;          // int[N]        65536
static const size_t OFF_ROWS  = 65536;      // int[N+1]      (pad)
static const size_t OFF_CURSOR= 131584;     // int[N]
static const size_t OFF_CSR   = 197120;     // int[E]        524288
static const size_t OFF_DIS   = 721408;     // float[N]
static const size_t OFF_ES    = 786944;     // float[4N]
static const size_t OFF_ED    = 1049088;    // float[4N]
static const size_t OFF_BNS   = 1311232;    // float[512]
static const size_t OFF_BNQ   = 1313280;    // float[512]
static const size_t OFF_GB    = 1315328;    // int[33]
static const size_t OFF_POOL  = 1315584;    // float[32*1024]
static const size_t OFF_XA1   = 1446656;    // float[5N]
static const size_t OFF_H1    = 1774336;    // float[64N]   4 MB
static const size_t OFF_AGG   = 5968640;    // float[64N]   4 MB
static const size_t OFF_H2    = 10162944;   // float[128N]  8 MB
static const size_t OFF_H3    = 18551552;   // float[256N]  16 MB
static const size_t OFF_HGAT  = 35328768;   // bf16[1024N]  32 MB (was fp32)
static const size_t OFF_XA4   = OFF_HGAT + 33554432; // float[256N] 16 MB
static const size_t OFF_H4    = OFF_XA4 + 16777216;  // float[512N] 32 MB
// total ≈ 114 MB

// ---------------- graph structure ----------------
__global__ void k_indeg(const int* __restrict__ dst, int* __restrict__ indeg) {
    int e = blockIdx.x * 256 + threadIdx.x;
    if (e < E_) atomicAdd(&indeg[dst[e]], 1);
}

__global__ void k_dis(const int* __restrict__ indeg, float* __restrict__ dis) {
    int i = blockIdx.x * 256 + threadIdx.x;
    if (i < N_) dis[i] = rsqrtf((float)indeg[i] + 1.0f);
}

__global__ __launch_bounds__(1024) void k_scan(const int* __restrict__ indeg,
                                               int* __restrict__ rows) {
    __shared__ int part[1024];
    int t = threadIdx.x;
    int base = t * 16;
    int local[16];
    int s = 0;
#pragma unroll
    for (int i = 0; i < 16; ++i) { local[i] = indeg[base + i]; s += local[i]; }
    part[t] = s;
    __syncthreads();
    for (int off = 1; off < 1024; off <<= 1) {
        int v = (t >= off) ? part[t - off] : 0;
        __syncthreads();
        part[t] += v;
        __syncthreads();
    }
    int run = (t == 0) ? 0 : part[t - 1];
#pragma unroll
    for (int i = 0; i < 16; ++i) { rows[base + i] = run; run += local[i]; }
    if (t == 1023) rows[N_] = run;
}

__global__ void k_fill(const int* __restrict__ src, const int* __restrict__ dst,
                       int* __restrict__ cursor, int* __restrict__ csr) {
    int e = blockIdx.x * 256 + threadIdx.x;
    if (e < E_) {
        int p = atomicAdd(&cursor[dst[e]], 1);
        csr[p] = src[e];
    }
}

__global__ void k_gbounds(const int* __restrict__ batch, int* __restrict__ gb) {
    int g = threadIdx.x;
    if (g > G_) return;
    if (g == G_) { gb[G_] = N_; return; }
    int lo = 0, hi = N_;
    while (lo < hi) { int mid = (lo + hi) >> 1; if (batch[mid] < g) lo = mid + 1; else hi = mid; }
    gb[g] = lo;
}

// ---------------- layer 1: GCN(5->64) ----------------
__global__ void k_gcn1_agg(const float* __restrict__ x, const float* __restrict__ dis,
                           const int* __restrict__ rows, const int* __restrict__ csr,
                           float* __restrict__ xa) {
    int i = blockIdx.x * 256 + threadIdx.x;
    if (i >= N_) return;
    float di = dis[i];
    float a0 = x[i*5+0]*di*di, a1 = x[i*5+1]*di*di, a2 = x[i*5+2]*di*di,
          a3 = x[i*5+3]*di*di, a4 = x[i*5+4]*di*di;
    int e0 = rows[i], e1 = rows[i+1];
    for (int e = e0; e < e1; ++e) {
        int s = csr[e];
        float w = dis[s] * di;
        a0 += x[s*5+0]*w; a1 += x[s*5+1]*w; a2 += x[s*5+2]*w;
        a3 += x[s*5+3]*w; a4 += x[s*5+4]*w;
    }
    xa[i*5+0]=a0; xa[i*5+1]=a1; xa[i*5+2]=a2; xa[i*5+3]=a3; xa[i*5+4]=a4;
}

__global__ void k_mm5(const float* __restrict__ xa, const float* __restrict__ w,
                      const float* __restrict__ b, float* __restrict__ out) {
    int idx = blockIdx.x * 256 + threadIdx.x;   // N*64
    int n = idx >> 6, m = idx & 63;
    float s = b[m];
#pragma unroll
    for (int k = 0; k < 5; ++k) s += xa[n*5+k] * w[k*64+m];
    out[idx] = s;
}

// ---------------- batchnorm ----------------
__global__ void k_bn_stats(const float* __restrict__ x, float* __restrict__ sum,
                           float* __restrict__ sumsq, int C, int rowsPerBlock) {
    int t = threadIdx.x;
    size_t base = (size_t)blockIdx.x * rowsPerBlock * C;
    size_t end  = base + (size_t)rowsPerBlock * C;
    if (C == 512) {
        float s0=0,q0=0,s1=0,q1=0;
        for (size_t f = base + t; f < end; f += 512) {
            float v = x[f];     s0 += v; q0 += v*v;
            float w = x[f+256]; s1 += w; q1 += w*w;
        }
        atomicAdd(&sum[t], s0);      atomicAdd(&sumsq[t], q0);
        atomicAdd(&sum[t+256], s1);  atomicAdd(&sumsq[t+256], q1);
    } else {
        float s0=0,q0=0;
        for (size_t f = base + t; f < end; f += 256) {
            float v = x[f]; s0 += v; q0 += v*v;
        }
        __shared__ float ls[256], lq[256];
        ls[t]=s0; lq[t]=q0;
        __syncthreads();
        if (t < C) {
            for (int j = t + C; j < 256; j += C) { s0 += ls[j]; q0 += lq[j]; }
            atomicAdd(&sum[t], s0); atomicAdd(&sumsq[t], q0);
        }
    }
}

__global__ void k_bn_apply(float* __restrict__ h, const float* __restrict__ sum,
                           const float* __restrict__ sumsq, const float* __restrict__ g,
                           const float* __restrict__ b, int C, int total) {
    int idx = blockIdx.x * 256 + threadIdx.x;
    if (idx >= total) return;
    int c = idx & (C - 1);
    const float invN = 1.0f / (float)N_;
    float mu  = sum[c] * invN;
    float var = sumsq[c] * invN - mu * mu;
    float v = (h[idx] - mu) * rsqrtf(var + EPSF) * g[c] + b[c];
    h[idx] = v > 0.f ? v : 0.f;
}

// ---------------- SAGE aggregate (mean) ----------------
__global__ void k_sage_agg(const float* __restrict__ h1, const int* __restrict__ rows,
                           const int* __restrict__ csr, float* __restrict__ agg) {
    int i = blockIdx.x * 4 + (threadIdx.x >> 6);
    int c = threadIdx.x & 63;
    int e0 = rows[i], e1 = rows[i+1];
    float s = 0.f;
    for (int e = e0; e < e1; ++e) s += h1[(size_t)csr[e]*64 + c];
    agg[(size_t)i*64 + c] = s / fmaxf((float)(e1 - e0), 1.0f);
}

// ---------------- generic tiled SGEMM: C[n,m] (+)= A[n,k] B[k,m] ----------------
// obf: write output as bf16 (used for hgat to halve GAT gather traffic)
__global__ __launch_bounds__(256) void k_gemm(const float* __restrict__ A,
                                              const float* __restrict__ B,
                                              const float* __restrict__ bias,
                                              float* __restrict__ C,
                                              int K, int M, int accum, int obf) {
    __shared__ float As[16][68];
    __shared__ float Bs[16][68];
    int tid = threadIdx.x;
    int tx = tid & 15, ty = tid >> 4;
    int row0 = blockIdx.y * 64, col0 = blockIdx.x * 64;
    float acc[4][4];
#pragma unroll
    for (int i = 0; i < 4; ++i)
#pragma unroll
        for (int j = 0; j < 4; ++j) acc[i][j] = 0.f;
    int lka = tid & 15, lra = tid >> 4;
    int lcb = tid & 63, lkb = tid >> 6;
    for (int k0 = 0; k0 < K; k0 += 16) {
#pragma unroll
        for (int it = 0; it < 4; ++it)
            As[lka][lra + it*16] = A[(size_t)(row0 + lra + it*16)*K + k0 + lka];
#pragma unroll
        for (int it = 0; it < 4; ++it)
            Bs[lkb + it*4][lcb] = B[(size_t)(k0 + lkb + it*4)*M + col0 + lcb];
        __syncthreads();
#pragma unroll
        for (int k = 0; k < 16; ++k) {
            float a0 = As[k][ty*4+0], a1 = As[k][ty*4+1],
                  a2 = As[k][ty*4+2], a3 = As[k][ty*4+3];
            float b0 = Bs[k][tx*4+0], b1 = Bs[k][tx*4+1],
                  b2 = Bs[k][tx*4+2], b3 = Bs[k][tx*4+3];
            acc[0][0] += a0*b0; acc[0][1] += a0*b1; acc[0][2] += a0*b2; acc[0][3] += a0*b3;
            acc[1][0] += a1*b0; acc[1][1] += a1*b1; acc[1][2] += a1*b2; acc[1][3] += a1*b3;
            acc[2][0] += a2*b0; acc[2][1] += a2*b1; acc[2][2] += a2*b2; acc[2][3] += a2*b3;
            acc[3][0] += a3*b0; acc[3][1] += a3*b1; acc[3][2] += a3*b2; acc[3][3] += a3*b3;
        }
        __syncthreads();
    }
    if (obf) {
        bf16u* Cb = (bf16u*)C;
#pragma unroll
        for (int i = 0; i < 4; ++i) {
            int r = row0 + ty*4 + i;
            ushort4 u;
            u.x = f2bf(acc[i][0]); u.y = f2bf(acc[i][1]);
            u.z = f2bf(acc[i][2]); u.w = f2bf(acc[i][3]);
            *(ushort4*)&Cb[(size_t)r*M + col0 + tx*4] = u;
        }
        return;
    }
#pragma unroll
    for (int i = 0; i < 4; ++i) {
        int r = row0 + ty*4 + i;
#pragma unroll
        for (int j = 0; j < 4; ++j) {
            int c = col0 + tx*4 + j;
            size_t idx = (size_t)r*M + c;
            float v = acc[i][j];
            if (bias)  v += bias[c];
            if (accum) v += C[idx];
            C[idx] = v;
        }
    }
}

// ---------------- GAT ----------------
__global__ __launch_bounds__(256) void k_gat_attn(const bf16u* __restrict__ hg,
                                                  const float* __restrict__ asrc,
                                                  const float* __restrict__ adst,
                                                  float* __restrict__ es,
                                                  float* __restrict__ ed) {
    __shared__ float2 red[256];
    int i = blockIdx.x, t = threadIdx.x;
    for (int h = 0; h < 4; ++h) {
        float hv = bf2f(hg[(size_t)i*1024 + h*256 + t]);
        float2 p; p.x = hv * asrc[h*256 + t]; p.y = hv * adst[h*256 + t];
        red[t] = p; __syncthreads();
        for (int s = 128; s > 0; s >>= 1) {
            if (t < s) { red[t].x += red[t+s].x; red[t].y += red[t+s].y; }
            __syncthreads();
        }
        if (t == 0) { es[i*4 + h] = red[0].x; ed[i*4 + h] = red[0].y; }
        __syncthreads();
    }
}

// Per-chunk shared softmax: logits staged once, max + exp computed once (not
// per-thread-redundantly); accumulate loop is ds_read_b128 broadcast + FMA.
// hgat in bf16 halves the dominant gather traffic (r3: 287 MB fetch, 85us).
#define GCH 256
__global__ __launch_bounds__(256) void k_gat_agg(const bf16u* __restrict__ hg,
                                                 const float* __restrict__ es,
                                                 const float* __restrict__ ed,
                                                 const int* __restrict__ rows,
                                                 const int* __restrict__ csr,
                                                 const float* __restrict__ gbias,
                                                 float* __restrict__ out) {
    __shared__ float4 se4[GCH];
    __shared__ int ssrc[GCH];
    int i = blockIdx.x, t = threadIdx.x;
    float edv0, edv1, edv2, edv3;
    {
        const float4 ev = *(const float4*)&ed[i*4];
        edv0 = ev.x; edv1 = ev.y; edv2 = ev.z; edv3 = ev.w;
    }
    float m0, m1, m2, m3, z0, z1, z2, z3, a0, a1, a2, a3;
    {
        const float4 sv = *(const float4*)&es[i*4];
        float e;
        e = sv.x + edv0; m0 = e >= 0.f ? e : 0.2f*e;
        e = sv.y + edv1; m1 = e >= 0.f ? e : 0.2f*e;
        e = sv.z + edv2; m2 = e >= 0.f ? e : 0.2f*e;
        e = sv.w + edv3; m3 = e >= 0.f ? e : 0.2f*e;
        z0 = z1 = z2 = z3 = 1.f;
        const bf16u* hp = hg + (size_t)i*1024 + t;
        a0 = bf2f(hp[0]); a1 = bf2f(hp[256]); a2 = bf2f(hp[512]); a3 = bf2f(hp[768]);
    }
    int e0 = rows[i], e1 = rows[i+1];
    for (int c0 = e0; c0 < e1; c0 += GCH) {
        int cn = min(GCH, e1 - c0);
        for (int j = t; j < cn; j += 256) {
            int s = csr[c0 + j];
            ssrc[j] = s;
            const float4 sv = *(const float4*)&es[s*4];
            float4 v;
            float e;
            e = sv.x + edv0; v.x = e >= 0.f ? e : 0.2f*e;
            e = sv.y + edv1; v.y = e >= 0.f ? e : 0.2f*e;
            e = sv.z + edv2; v.z = e >= 0.f ? e : 0.2f*e;
            e = sv.w + edv3; v.w = e >= 0.f ? e : 0.2f*e;
            se4[j] = v;
        }
        __syncthreads();
        float nm0 = m0, nm1 = m1, nm2 = m2, nm3 = m3;
        for (int j = 0; j < cn; ++j) {
            float4 v = se4[j];
            nm0 = fmaxf(nm0, v.x); nm1 = fmaxf(nm1, v.y);
            nm2 = fmaxf(nm2, v.z); nm3 = fmaxf(nm3, v.w);
        }
        {
            float sc;
            sc = __expf(m0 - nm0); z0 *= sc; a0 *= sc; m0 = nm0;
            sc = __expf(m1 - nm1); z1 *= sc; a1 *= sc; m1 = nm1;
            sc = __expf(m2 - nm2); z2 *= sc; a2 *= sc; m2 = nm2;
            sc = __expf(m3 - nm3); z3 *= sc; a3 *= sc; m3 = nm3;
        }
        __syncthreads();   // everyone done reading raw logits
        for (int j = t; j < cn; j += 256) {
            float4 v = se4[j];
            v.x = __expf(v.x - nm0); v.y = __expf(v.y - nm1);
            v.z = __expf(v.z - nm2); v.w = __expf(v.w - nm3);
            se4[j] = v;
        }
        __syncthreads();
        for (int j = 0; j < cn; ++j) {
            float4 ex = se4[j];
            const bf16u* hp = hg + (size_t)ssrc[j]*1024 + t;
            z0 += ex.x; a0 += ex.x * bf2f(hp[0]);
            z1 += ex.y; a1 += ex.y * bf2f(hp[256]);
            z2 += ex.z; a2 += ex.z * bf2f(hp[512]);
            z3 += ex.w; a3 += ex.w * bf2f(hp[768]);
        }
        __syncthreads();
    }
    float o = 0.25f * (a0/z0 + a1/z1 + a2/z2 + a3/z3);
    out[(size_t)i*256 + t] = o + gbias[t];
}

// ---------------- layer 4: GCN(256->512) aggregate ----------------
__global__ __launch_bounds__(256) void k_gcn4_agg(const float* __restrict__ h3,
                                                  const float* __restrict__ dis,
                                                  const int* __restrict__ rows,
                                                  const int* __restrict__ csr,
                                                  float* __restrict__ xa) {
    int i = blockIdx.x, t = threadIdx.x;
    float di = dis[i];
    float a = h3[(size_t)i*256 + t] * di * di;
    int e0 = rows[i], e1 = rows[i+1];
    for (int e = e0; e < e1; ++e) {
        int s = csr[e];
        a += h3[(size_t)s*256 + t] * (dis[s] * di);
    }
    xa[(size_t)i*256 + t] = a;
}

// ---------------- pooling ----------------
__global__ void k_pool(const float* __restrict__ h4, const int* __restrict__ gb,
                       float* __restrict__ pooled) {
    int g = blockIdx.y;
    int t = threadIdx.x;
    int r0g = gb[g], r1g = gb[g+1];
    int n = r1g - r0g;
    if (n <= 0) return;
    int per = (n + 15) >> 4;
    int r0 = r0g + blockIdx.x * per;
    int r1 = min(r0 + per, r1g);
    if (r0 >= r1) return;
    float s0=0.f, s1=0.f, m0=0.f, m1=0.f;   // h4 >= 0 post-ReLU: max init 0 valid
    for (int r = r0; r < r1; ++r) {
        float v = h4[(size_t)r*512 + t];       s0 += v; m0 = fmaxf(m0, v);
        float w = h4[(size_t)r*512 + 256 + t]; s1 += w; m1 = fmaxf(m1, w);
    }
    atomicAdd(&pooled[g*1024 + t], s0);
    atomicAdd(&pooled[g*1024 + 256 + t], s1);
    atomicMax((int*)&pooled[g*1024 + 512 + t],  __float_as_int(m0));
    atomicMax((int*)&pooled[g*1024 + 768 + t],  __float_as_int(m1));
}

__global__ void k_pool_fin(float* __restrict__ pooled, const int* __restrict__ gb) {
    int g = blockIdx.x, t = threadIdx.x;    // 512 threads
    int cnt = gb[g+1] - gb[g];
    pooled[g*1024 + t] *= 1.0f / fmaxf((float)cnt, 1.0f);
}

// ---------------- FC (K-split, float4, atomic reduce) ----------------
#define FCKZ 16
#define FCKC (1024 / FCKZ)   // 64

__global__ void k_fc_init(const float* __restrict__ b, float* __restrict__ out) {
    int i = blockIdx.x * 256 + threadIdx.x;   // 32*1024
    out[i] = b[i & 1023];
}

__global__ __launch_bounds__(256) void k_fc2(const float* __restrict__ pooled,
                                             const float* __restrict__ w,
                                             float* __restrict__ out) {
    __shared__ float pr[FCKC];
    int g = blockIdx.x;
    int z = blockIdx.y;
    int t = threadIdx.x;
    int k0 = z * FCKC;
    if (t < FCKC) pr[t] = pooled[g * 1024 + k0 + t];
    __syncthreads();
    int m0 = t * 4;
    float ax = 0.f, ay = 0.f, az = 0.f, aw = 0.f;
#pragma unroll 8
    for (int k = 0; k < FCKC; ++k) {
        const float4 wv = *(const float4*)&w[(size_t)(k0 + k) * 1024 + m0];
        float p = pr[k];
        ax += p * wv.x; ay += p * wv.y; az += p * wv.z; aw += p * wv.w;
    }
    atomicAdd(&out[g * 1024 + m0 + 0], ax);
    atomicAdd(&out[g * 1024 + m0 + 1], ay);
    atomicAdd(&out[g * 1024 + m0 + 2], az);
    atomicAdd(&out[g * 1024 + m0 + 3], aw);
}

// ---------------- host ----------------
extern "C" void kernel_launch(void* const* d_in, const int* in_sizes, int n_in,
                              void* d_out, int out_size, void* d_ws, size_t ws_size,
                              hipStream_t stream) {
    (void)in_sizes; (void)n_in; (void)out_size; (void)ws_size;
    const float* x       = (const float*)d_in[0];
    const int*   ei      = (const int*)d_in[1];
    const int*   batch   = (const int*)d_in[2];
    const float* gcn1_w  = (const float*)d_in[3];
    const float* gcn1_b  = (const float*)d_in[4];
    const float* sage_wl = (const float*)d_in[5];
    const float* sage_wr = (const float*)d_in[6];
    const float* sage_b  = (const float*)d_in[7];
    const float* gat_w   = (const float*)d_in[8];
    const float* gat_as  = (const float*)d_in[9];
    const float* gat_ad  = (const float*)d_in[10];
    const float* gat_b   = (const float*)d_in[11];
    const float* gcn4_w  = (const float*)d_in[12];
    const float* gcn4_b  = (const float*)d_in[13];
    const float* bn1_g   = (const float*)d_in[14];
    const float* bn1_b   = (const float*)d_in[15];
    const float* bn2_g   = (const float*)d_in[16];
    const float* bn2_b   = (const float*)d_in[17];
    const float* bn3_g   = (const float*)d_in[18];
    const float* bn3_b   = (const float*)d_in[19];
    const float* bn4_g   = (const float*)d_in[20];
    const float* bn4_b   = (const float*)d_in[21];
    const float* fc_w    = (const float*)d_in[22];
    const float* fc_b    = (const float*)d_in[23];
    float* out = (float*)d_out;

    char* w8 = (char*)d_ws;
    int*   indeg  = (int*)(w8 + OFF_INDEG);
    int*   rows   = (int*)(w8 + OFF_ROWS);
    int*   cursor = (int*)(w8 + OFF_CURSOR);
    int*   csr    = (int*)(w8 + OFF_CSR);
    float* dis    = (float*)(w8 + OFF_DIS);
    float* es     = (float*)(w8 + OFF_ES);
    float* ed     = (float*)(w8 + OFF_ED);
    float* bns    = (float*)(w8 + OFF_BNS);
    float* bnq    = (float*)(w8 + OFF_BNQ);
    int*   gb     = (int*)(w8 + OFF_GB);
    float* pooled = (float*)(w8 + OFF_POOL);
    float* xa1    = (float*)(w8 + OFF_XA1);
    float* h1     = (float*)(w8 + OFF_H1);
    float* agg    = (float*)(w8 + OFF_AGG);
    float* h2     = (float*)(w8 + OFF_H2);
    float* h3     = (float*)(w8 + OFF_H3);
    bf16u* hgat   = (bf16u*)(w8 + OFF_HGAT);
    float* xa4    = (float*)(w8 + OFF_XA4);
    float* h4     = (float*)(w8 + OFF_H4);

    const int* srcE = ei;        // edge_index[0,:]
    const int* dstE = ei + E_;   // edge_index[1,:]

    const int BNB = 512;
    const int BNR = N_ / BNB;

    // ---- graph structure ----
    hipMemsetAsync(indeg, 0, N_ * sizeof(int), stream);
    k_indeg<<<E_/256, 256, 0, stream>>>(dstE, indeg);
    k_dis<<<N_/256, 256, 0, stream>>>(indeg, dis);
    k_scan<<<1, 1024, 0, stream>>>(indeg, rows);
    hipMemcpyAsync(cursor, rows, N_ * sizeof(int), hipMemcpyDeviceToDevice, stream);
    k_fill<<<E_/256, 256, 0, stream>>>(srcE, dstE, cursor, csr);
    k_gbounds<<<1, 64, 0, stream>>>(batch, gb);

    // ---- layer 1: GCN 5->64, BN, ReLU ----
    k_gcn1_agg<<<N_/256, 256, 0, stream>>>(x, dis, rows, csr, xa1);
    k_mm5<<<(N_*64)/256, 256, 0, stream>>>(xa1, gcn1_w, gcn1_b, h1);
    hipMemsetAsync(bns, 0, 4096, stream);
    k_bn_stats<<<BNB, 256, 0, stream>>>(h1, bns, bnq, 64, BNR);
    k_bn_apply<<<(N_*64)/256, 256, 0, stream>>>(h1, bns, bnq, bn1_g, bn1_b, 64, N_*64);

    // ---- layer 2: SAGE 64->128, BN, ReLU ----
    k_sage_agg<<<N_/4, 256, 0, stream>>>(h1, rows, csr, agg);
    {
        dim3 grid(128/64, N_/64);
        k_gemm<<<grid, 256, 0, stream>>>(agg, sage_wl, nullptr, h2, 64, 128, 0, 0);
        k_gemm<<<grid, 256, 0, stream>>>(h1, sage_wr, sage_b, h2, 64, 128, 1, 0);
    }
    hipMemsetAsync(bns, 0, 4096, stream);
    k_bn_stats<<<BNB, 256, 0, stream>>>(h2, bns, bnq, 128, BNR);
    k_bn_apply<<<(N_*128)/256, 256, 0, stream>>>(h2, bns, bnq, bn2_g, bn2_b, 128, N_*128);

    // ---- layer 3: GAT 128->4x256 (head-mean -> 256), BN, ReLU ----
    {
        dim3 grid(1024/64, N_/64);
        k_gemm<<<grid, 256, 0, stream>>>(h2, gat_w, nullptr, (float*)hgat, 128, 1024, 0, 1);
    }
    k_gat_attn<<<N_, 256, 0, stream>>>(hgat, gat_as, gat_ad, es, ed);
    k_gat_agg<<<N_, 256, 0, stream>>>(hgat, es, ed, rows, csr, gat_b, h3);
    hipMemsetAsync(bns, 0, 4096, stream);
    k_bn_stats<<<BNB, 256, 0, stream>>>(h3, bns, bnq, 256, BNR);
    k_bn_apply<<<(N_*256)/256, 256, 0, stream>>>(h3, bns, bnq, bn3_g, bn3_b, 256, N_*256);

    // ---- layer 4: GCN 256->512, BN, ReLU ----
    k_gcn4_agg<<<N_, 256, 0, stream>>>(h3, dis, rows, csr, xa4);
    {
        dim3 grid(512/64, N_/64);
        k_gemm<<<grid, 256, 0, stream>>>(xa4, gcn4_w, gcn4_b, h4, 256, 512, 0, 0);
    }
    hipMemsetAsync(bns, 0, 4096, stream);
    k_bn_stats<<<BNB, 256, 0, stream>>>(h4, bns, bnq, 512, BNR);
    k_bn_apply<<<(N_*512)/256, 256, 0, stream>>>(h4, bns, bnq, bn4_g, bn4_b, 512, N_*512);

    // ---- pooling (mean | max) -> [32,1024] ----
    hipMemsetAsync(pooled, 0, 32 * 1024 * sizeof(float), stream);
    {
        dim3 grid(16, G_);
        k_pool<<<grid, 256, 0, stream>>>(h4, gb, pooled);
    }
    k_pool_fin<<<G_, 512, 0, stream>>>(pooled, gb);

    // ---- FC 1024->1024 ----
    k_fc_init<<<(G_*1024)/256, 256, 0, stream>>>(fc_b, out);
    {
        dim3 grid(G_, FCKZ);
        k_fc2<<<grid, 256, 0, stream>>>(pooled, fc_w, out);
    }
}

// Round 5
// 489.558 us; speedup vs baseline: 2.0668x; 1.1739x over previous
//
#include <hip/hip_runtime.h>

#define N_ 16384
#define E_ 131072
#define G_ 32
#define EPSF 1e-5f

typedef unsigned short bf16u;
typedef __attribute__((ext_vector_type(8))) short s8v;   // 8 bf16 (4 VGPRs)
typedef __attribute__((ext_vector_type(4))) float f4v;   // 4 fp32 acc

__device__ __forceinline__ bf16u f2bf(float v) {
    union { float f; unsigned u; } x; x.f = v;
    unsigned r = x.u + 0x7FFF + ((x.u >> 16) & 1);   // RNE
    return (bf16u)(r >> 16);
}
__device__ __forceinline__ float bf2f(bf16u u) {
    union { unsigned u; float f; } x; x.u = (unsigned)u << 16;
    return x.f;
}

// ---------------- workspace layout (bytes) ----------------
static const size_t OFF_INDEG = 0;          // int[N]        65536
static const size_t OFF_ROWS  = 65536;      // int[N+1]      (pad)
static const size_t OFF_CURSOR= 131584;     // int[N]
static const size_t OFF_CSR   = 197120;     // int[E]        524288
static const size_t OFF_DIS   = 721408;     // float[N]
static const size_t OFF_ES    = 786944;     // float[4N]
static const size_t OFF_ED    = 1049088;    // float[4N]
static const size_t OFF_BNS   = 1311232;    // float[512]
static const size_t OFF_BNQ   = 1313280;    // float[512]
static const size_t OFF_GB    = 1315328;    // int[33]
static const size_t OFF_POOL  = 1315584;    // float[32*1024]
static const size_t OFF_XA1   = 1446656;    // float[5N]
static const size_t OFF_H1    = 1774336;    // float[64N]   4 MB
static const size_t OFF_AGG   = 5968640;    // float[64N]   4 MB
static const size_t OFF_H2    = 10162944;   // float[128N]  8 MB
static const size_t OFF_H3    = 18551552;   // float[256N]  16 MB
static const size_t OFF_HGAT  = 35328768;   // bf16[1024N]  32 MB
static const size_t OFF_XA4B  = OFF_HGAT;             // bf16[256N] 8 MB (hgat dead by then)
static const size_t OFF_H2B   = OFF_HGAT + 33554432;  // bf16[128N] 4 MB (old xa4 slot)
static const size_t OFF_WT1   = OFF_H2B + 4194304;    // bf16[1024*128] 256 KB (gat_w^T)
static const size_t OFF_WT2   = OFF_WT1 + 262144;     // bf16[512*256]  256 KB (gcn4_w^T)
static const size_t OFF_H4    = OFF_HGAT + 50331648;  // float[512N] 32 MB (unchanged)
// total ≈ 114 MB (same footprint as round 4)

// ---------------- graph structure ----------------
__global__ void k_indeg(const int* __restrict__ dst, int* __restrict__ indeg) {
    int e = blockIdx.x * 256 + threadIdx.x;
    if (e < E_) atomicAdd(&indeg[dst[e]], 1);
}

__global__ void k_dis(const int* __restrict__ indeg, float* __restrict__ dis) {
    int i = blockIdx.x * 256 + threadIdx.x;
    if (i < N_) dis[i] = rsqrtf((float)indeg[i] + 1.0f);
}

__global__ __launch_bounds__(1024) void k_scan(const int* __restrict__ indeg,
                                               int* __restrict__ rows) {
    __shared__ int part[1024];
    int t = threadIdx.x;
    int base = t * 16;
    int local[16];
    int s = 0;
#pragma unroll
    for (int i = 0; i < 16; ++i) { local[i] = indeg[base + i]; s += local[i]; }
    part[t] = s;
    __syncthreads();
    for (int off = 1; off < 1024; off <<= 1) {
        int v = (t >= off) ? part[t - off] : 0;
        __syncthreads();
        part[t] += v;
        __syncthreads();
    }
    int run = (t == 0) ? 0 : part[t - 1];
#pragma unroll
    for (int i = 0; i < 16; ++i) { rows[base + i] = run; run += local[i]; }
    if (t == 1023) rows[N_] = run;
}

__global__ void k_fill(const int* __restrict__ src, const int* __restrict__ dst,
                       int* __restrict__ cursor, int* __restrict__ csr) {
    int e = blockIdx.x * 256 + threadIdx.x;
    if (e < E_) {
        int p = atomicAdd(&cursor[dst[e]], 1);
        csr[p] = src[e];
    }
}

__global__ void k_gbounds(const int* __restrict__ batch, int* __restrict__ gb) {
    int g = threadIdx.x;
    if (g > G_) return;
    if (g == G_) { gb[G_] = N_; return; }
    int lo = 0, hi = N_;
    while (lo < hi) { int mid = (lo + hi) >> 1; if (batch[mid] < g) lo = mid + 1; else hi = mid; }
    gb[g] = lo;
}

// ---------------- weight transpose+convert: w[K][M] -> wT[M][K] bf16 ----------------
__global__ void k_wconv(const float* __restrict__ w, bf16u* __restrict__ wT,
                        int K, int M) {
    int idx = blockIdx.x * 256 + threadIdx.x;   // M*K total
    int m = idx / K, k = idx - m * K;
    wT[idx] = f2bf(w[(size_t)k * M + m]);
}

// ---------------- layer 1: GCN(5->64) ----------------
__global__ void k_gcn1_agg(const float* __restrict__ x, const float* __restrict__ dis,
                           const int* __restrict__ rows, const int* __restrict__ csr,
                           float* __restrict__ xa) {
    int i = blockIdx.x * 256 + threadIdx.x;
    if (i >= N_) return;
    float di = dis[i];
    float a0 = x[i*5+0]*di*di, a1 = x[i*5+1]*di*di, a2 = x[i*5+2]*di*di,
          a3 = x[i*5+3]*di*di, a4 = x[i*5+4]*di*di;
    int e0 = rows[i], e1 = rows[i+1];
    for (int e = e0; e < e1; ++e) {
        int s = csr[e];
        float w = dis[s] * di;
        a0 += x[s*5+0]*w; a1 += x[s*5+1]*w; a2 += x[s*5+2]*w;
        a3 += x[s*5+3]*w; a4 += x[s*5+4]*w;
    }
    xa[i*5+0]=a0; xa[i*5+1]=a1; xa[i*5+2]=a2; xa[i*5+3]=a3; xa[i*5+4]=a4;
}

__global__ void k_mm5(const float* __restrict__ xa, const float* __restrict__ w,
                      const float* __restrict__ b, float* __restrict__ out) {
    int idx = blockIdx.x * 256 + threadIdx.x;   // N*64
    int n = idx >> 6, m = idx & 63;
    float s = b[m];
#pragma unroll
    for (int k = 0; k < 5; ++k) s += xa[n*5+k] * w[k*64+m];
    out[idx] = s;
}

// ---------------- batchnorm ----------------
__global__ void k_bn_stats(const float* __restrict__ x, float* __restrict__ sum,
                           float* __restrict__ sumsq, int C, int rowsPerBlock) {
    int t = threadIdx.x;
    size_t base = (size_t)blockIdx.x * rowsPerBlock * C;
    size_t end  = base + (size_t)rowsPerBlock * C;
    if (C == 512) {
        float s0=0,q0=0,s1=0,q1=0;
        for (size_t f = base + t; f < end; f += 512) {
            float v = x[f];     s0 += v; q0 += v*v;
            float w = x[f+256]; s1 += w; q1 += w*w;
        }
        atomicAdd(&sum[t], s0);      atomicAdd(&sumsq[t], q0);
        atomicAdd(&sum[t+256], s1);  atomicAdd(&sumsq[t+256], q1);
    } else {
        float s0=0,q0=0;
        for (size_t f = base + t; f < end; f += 256) {
            float v = x[f]; s0 += v; q0 += v*v;
        }
        __shared__ float ls[256], lq[256];
        ls[t]=s0; lq[t]=q0;
        __syncthreads();
        if (t < C) {
            for (int j = t + C; j < 256; j += C) { s0 += ls[j]; q0 += lq[j]; }
            atomicAdd(&sum[t], s0); atomicAdd(&sumsq[t], q0);
        }
    }
}

// optional bf16 mirror (hb) for MFMA consumers
__global__ void k_bn_apply(float* __restrict__ h, const float* __restrict__ sum,
                           const float* __restrict__ sumsq, const float* __restrict__ g,
                           const float* __restrict__ b, int C, int total,
                           bf16u* __restrict__ hb) {
    int idx = blockIdx.x * 256 + threadIdx.x;
    if (idx >= total) return;
    int c = idx & (C - 1);
    const float invN = 1.0f / (float)N_;
    float mu  = sum[c] * invN;
    float var = sumsq[c] * invN - mu * mu;
    float v = (h[idx] - mu) * rsqrtf(var + EPSF) * g[c] + b[c];
    v = v > 0.f ? v : 0.f;
    h[idx] = v;
    if (hb) hb[idx] = f2bf(v);
}

// ---------------- SAGE aggregate (mean) ----------------
__global__ void k_sage_agg(const float* __restrict__ h1, const int* __restrict__ rows,
                           const int* __restrict__ csr, float* __restrict__ agg) {
    int i = blockIdx.x * 4 + (threadIdx.x >> 6);
    int c = threadIdx.x & 63;
    int e0 = rows[i], e1 = rows[i+1];
    float s = 0.f;
    for (int e = e0; e < e1; ++e) s += h1[(size_t)csr[e]*64 + c];
    agg[(size_t)i*64 + c] = s / fmaxf((float)(e1 - e0), 1.0f);
}

// ---------------- fp32 tiled SGEMM (kept for SAGE: K=64, M=128) ----------------
__global__ __launch_bounds__(256) void k_gemm(const float* __restrict__ A,
                                              const float* __restrict__ B,
                                              const float* __restrict__ bias,
                                              float* __restrict__ C,
                                              int K, int M, int accum) {
    __shared__ float As[16][68];
    __shared__ float Bs[16][68];
    int tid = threadIdx.x;
    int tx = tid & 15, ty = tid >> 4;
    int row0 = blockIdx.y * 64, col0 = blockIdx.x * 64;
    float acc[4][4];
#pragma unroll
    for (int i = 0; i < 4; ++i)
#pragma unroll
        for (int j = 0; j < 4; ++j) acc[i][j] = 0.f;
    int lka = tid & 15, lra = tid >> 4;
    int lcb = tid & 63, lkb = tid >> 6;
    for (int k0 = 0; k0 < K; k0 += 16) {
#pragma unroll
        for (int it = 0; it < 4; ++it)
            As[lka][lra + it*16] = A[(size_t)(row0 + lra + it*16)*K + k0 + lka];
#pragma unroll
        for (int it = 0; it < 4; ++it)
            Bs[lkb + it*4][lcb] = B[(size_t)(k0 + lkb + it*4)*M + col0 + lcb];
        __syncthreads();
#pragma unroll
        for (int k = 0; k < 16; ++k) {
            float a0 = As[k][ty*4+0], a1 = As[k][ty*4+1],
                  a2 = As[k][ty*4+2], a3 = As[k][ty*4+3];
            float b0 = Bs[k][tx*4+0], b1 = Bs[k][tx*4+1],
                  b2 = Bs[k][tx*4+2], b3 = Bs[k][tx*4+3];
            acc[0][0] += a0*b0; acc[0][1] += a0*b1; acc[0][2] += a0*b2; acc[0][3] += a0*b3;
            acc[1][0] += a1*b0; acc[1][1] += a1*b1; acc[1][2] += a1*b2; acc[1][3] += a1*b3;
            acc[2][0] += a2*b0; acc[2][1] += a2*b1; acc[2][2] += a2*b2; acc[2][3] += a2*b3;
            acc[3][0] += a3*b0; acc[3][1] += a3*b1; acc[3][2] += a3*b2; acc[3][3] += a3*b3;
        }
        __syncthreads();
    }
#pragma unroll
    for (int i = 0; i < 4; ++i) {
        int r = row0 + ty*4 + i;
#pragma unroll
        for (int j = 0; j < 4; ++j) {
            int c = col0 + tx*4 + j;
            size_t idx = (size_t)r*M + c;
            float v = acc[i][j];
            if (bias)  v += bias[c];
            if (accum) v += C[idx];
            C[idx] = v;
        }
    }
}

// ---------------- bf16 MFMA GEMM: C[n,m] = A[n,k] * BT[m,k]^T (+bias) ----------------
// 128x128 tile, BK=32, 4 waves each computing a 64x64 subtile via 4x4
// mfma_f32_16x16x32_bf16. Layouts per guide (m89/m91/m120):
//   A-frag  A[m=lane&15][k=quad*8+j], B-frag B[k=quad*8+j][n=lane&15],
//   C/D     col=lane&15, row=quad*4+reg.
// LDS [128][40] bf16 (pad 8): frag reads and staging writes are <=2-way
// bank-aliased (free per m136).
__global__ __launch_bounds__(256) void k_gemm_mfma(const bf16u* __restrict__ A,
                                                   const bf16u* __restrict__ BT,
                                                   const float* __restrict__ bias,
                                                   float* __restrict__ C,
                                                   int K, int M, int obf) {
    __shared__ bf16u As[128][40];
    __shared__ bf16u Bs[128][40];
    int tid = threadIdx.x;
    int wave = tid >> 6, lane = tid & 63;
    int wr = (wave >> 1) * 64, wc = (wave & 1) * 64;
    int row0 = blockIdx.y * 128, col0 = blockIdx.x * 128;
    f4v acc[4][4];
#pragma unroll
    for (int i = 0; i < 4; ++i)
#pragma unroll
        for (int j = 0; j < 4; ++j) acc[i][j] = (f4v)0.0f;

    int sr = tid >> 1;             // 0..127
    int sh = (tid & 1) * 16;       // k-half within BK

    int lr = lane & 15, lq = lane >> 4;

    for (int k0 = 0; k0 < K; k0 += 32) {
        const bf16u* ap = A + (size_t)(row0 + sr) * K + k0 + sh;
        *(uint4*)&As[sr][sh]     = *(const uint4*)ap;
        *(uint4*)&As[sr][sh + 8] = *(const uint4*)(ap + 8);
        const bf16u* bp = BT + (size_t)(col0 + sr) * K + k0 + sh;
        *(uint4*)&Bs[sr][sh]     = *(const uint4*)bp;
        *(uint4*)&Bs[sr][sh + 8] = *(const uint4*)(bp + 8);
        __syncthreads();
        s8v af[4], bfr[4];
#pragma unroll
        for (int i = 0; i < 4; ++i)
            af[i] = *(const s8v*)&As[wr + i*16 + lr][lq*8];
#pragma unroll
        for (int j = 0; j < 4; ++j)
            bfr[j] = *(const s8v*)&Bs[wc + j*16 + lr][lq*8];
#pragma unroll
        for (int i = 0; i < 4; ++i)
#pragma unroll
            for (int j = 0; j < 4; ++j)
                acc[i][j] = __builtin_amdgcn_mfma_f32_16x16x32_bf16(af[i], bfr[j], acc[i][j], 0, 0, 0);
        __syncthreads();
    }

    if (obf) {
        bf16u* Cb = (bf16u*)C;
#pragma unroll
        for (int i = 0; i < 4; ++i)
#pragma unroll
            for (int j = 0; j < 4; ++j) {
                int col = col0 + wc + j*16 + lr;
#pragma unroll
                for (int r = 0; r < 4; ++r) {
                    int row = row0 + wr + i*16 + lq*4 + r;
                    Cb[(size_t)row * M + col] = f2bf(acc[i][j][r]);
                }
            }
    } else {
#pragma unroll
        for (int i = 0; i < 4; ++i)
#pragma unroll
            for (int j = 0; j < 4; ++j) {
                int col = col0 + wc + j*16 + lr;
                float bv = bias ? bias[col] : 0.f;
#pragma unroll
                for (int r = 0; r < 4; ++r) {
                    int row = row0 + wr + i*16 + lq*4 + r;
                    C[(size_t)row * M + col] = acc[i][j][r] + bv;
                }
            }
    }
}

// ---------------- GAT ----------------
__global__ __launch_bounds__(256) void k_gat_attn(const bf16u* __restrict__ hg,
                                                  const float* __restrict__ asrc,
                                                  const float* __restrict__ adst,
                                                  float* __restrict__ es,
                                                  float* __restrict__ ed) {
    __shared__ float2 red[256];
    int i = blockIdx.x, t = threadIdx.x;
    for (int h = 0; h < 4; ++h) {
        float hv = bf2f(hg[(size_t)i*1024 + h*256 + t]);
        float2 p; p.x = hv * asrc[h*256 + t]; p.y = hv * adst[h*256 + t];
        red[t] = p; __syncthreads();
        for (int s = 128; s > 0; s >>= 1) {
            if (t < s) { red[t].x += red[t+s].x; red[t].y += red[t+s].y; }
            __syncthreads();
        }
        if (t == 0) { es[i*4 + h] = red[0].x; ed[i*4 + h] = red[0].y; }
        __syncthreads();
    }
}

#define GCH 256
__global__ __launch_bounds__(256) void k_gat_agg(const bf16u* __restrict__ hg,
                                                 const float* __restrict__ es,
                                                 const float* __restrict__ ed,
                                                 const int* __restrict__ rows,
                                                 const int* __restrict__ csr,
                                                 const float* __restrict__ gbias,
                                                 float* __restrict__ out) {
    __shared__ float4 se4[GCH];
    __shared__ int ssrc[GCH];
    int i = blockIdx.x, t = threadIdx.x;
    float edv0, edv1, edv2, edv3;
    {
        const float4 ev = *(const float4*)&ed[i*4];
        edv0 = ev.x; edv1 = ev.y; edv2 = ev.z; edv3 = ev.w;
    }
    float m0, m1, m2, m3, z0, z1, z2, z3, a0, a1, a2, a3;
    {
        const float4 sv = *(const float4*)&es[i*4];
        float e;
        e = sv.x + edv0; m0 = e >= 0.f ? e : 0.2f*e;
        e = sv.y + edv1; m1 = e >= 0.f ? e : 0.2f*e;
        e = sv.z + edv2; m2 = e >= 0.f ? e : 0.2f*e;
        e = sv.w + edv3; m3 = e >= 0.f ? e : 0.2f*e;
        z0 = z1 = z2 = z3 = 1.f;
        const bf16u* hp = hg + (size_t)i*1024 + t;
        a0 = bf2f(hp[0]); a1 = bf2f(hp[256]); a2 = bf2f(hp[512]); a3 = bf2f(hp[768]);
    }
    int e0 = rows[i], e1 = rows[i+1];
    for (int c0 = e0; c0 < e1; c0 += GCH) {
        int cn = min(GCH, e1 - c0);
        for (int j = t; j < cn; j += 256) {
            int s = csr[c0 + j];
            ssrc[j] = s;
            const float4 sv = *(const float4*)&es[s*4];
            float4 v;
            float e;
            e = sv.x + edv0; v.x = e >= 0.f ? e : 0.2f*e;
            e = sv.y + edv1; v.y = e >= 0.f ? e : 0.2f*e;
            e = sv.z + edv2; v.z = e >= 0.f ? e : 0.2f*e;
            e = sv.w + edv3; v.w = e >= 0.f ? e : 0.2f*e;
            se4[j] = v;
        }
        __syncthreads();
        float nm0 = m0, nm1 = m1, nm2 = m2, nm3 = m3;
        for (int j = 0; j < cn; ++j) {
            float4 v = se4[j];
            nm0 = fmaxf(nm0, v.x); nm1 = fmaxf(nm1, v.y);
            nm2 = fmaxf(nm2, v.z); nm3 = fmaxf(nm3, v.w);
        }
        {
            float sc;
            sc = __expf(m0 - nm0); z0 *= sc; a0 *= sc; m0 = nm0;
            sc = __expf(m1 - nm1); z1 *= sc; a1 *= sc; m1 = nm1;
            sc = __expf(m2 - nm2); z2 *= sc; a2 *= sc; m2 = nm2;
            sc = __expf(m3 - nm3); z3 *= sc; a3 *= sc; m3 = nm3;
        }
        __syncthreads();
        for (int j = t; j < cn; j += 256) {
            float4 v = se4[j];
            v.x = __expf(v.x - nm0); v.y = __expf(v.y - nm1);
            v.z = __expf(v.z - nm2); v.w = __expf(v.w - nm3);
            se4[j] = v;
        }
        __syncthreads();
        for (int j = 0; j < cn; ++j) {
            float4 ex = se4[j];
            const bf16u* hp = hg + (size_t)ssrc[j]*1024 + t;
            z0 += ex.x; a0 += ex.x * bf2f(hp[0]);
            z1 += ex.y; a1 += ex.y * bf2f(hp[256]);
            z2 += ex.z; a2 += ex.z * bf2f(hp[512]);
            z3 += ex.w; a3 += ex.w * bf2f(hp[768]);
        }
        __syncthreads();
    }
    float o = 0.25f * (a0/z0 + a1/z1 + a2/z2 + a3/z3);
    out[(size_t)i*256 + t] = o + gbias[t];
}

// ---------------- layer 4: GCN(256->512) aggregate -> bf16 ----------------
__global__ __launch_bounds__(256) void k_gcn4_agg(const float* __restrict__ h3,
                                                  const float* __restrict__ dis,
                                                  const int* __restrict__ rows,
                                                  const int* __restrict__ csr,
                                                  bf16u* __restrict__ xab) {
    int i = blockIdx.x, t = threadIdx.x;
    float di = dis[i];
    float a = h3[(size_t)i*256 + t] * di * di;
    int e0 = rows[i], e1 = rows[i+1];
    for (int e = e0; e < e1; ++e) {
        int s = csr[e];
        a += h3[(size_t)s*256 + t] * (dis[s] * di);
    }
    xab[(size_t)i*256 + t] = f2bf(a);
}

// ---------------- pooling ----------------
__global__ void k_pool(const float* __restrict__ h4, const int* __restrict__ gb,
                       float* __restrict__ pooled) {
    int g = blockIdx.y;
    int t = threadIdx.x;
    int r0g = gb[g], r1g = gb[g+1];
    int n = r1g - r0g;
    if (n <= 0) return;
    int per = (n + 15) >> 4;
    int r0 = r0g + blockIdx.x * per;
    int r1 = min(r0 + per, r1g);
    if (r0 >= r1) return;
    float s0=0.f, s1=0.f, m0=0.f, m1=0.f;   // h4 >= 0 post-ReLU: max init 0 valid
    for (int r = r0; r < r1; ++r) {
        float v = h4[(size_t)r*512 + t];       s0 += v; m0 = fmaxf(m0, v);
        float w = h4[(size_t)r*512 + 256 + t]; s1 += w; m1 = fmaxf(m1, w);
    }
    atomicAdd(&pooled[g*1024 + t], s0);
    atomicAdd(&pooled[g*1024 + 256 + t], s1);
    atomicMax((int*)&pooled[g*1024 + 512 + t],  __float_as_int(m0));
    atomicMax((int*)&pooled[g*1024 + 768 + t],  __float_as_int(m1));
}

__global__ void k_pool_fin(float* __restrict__ pooled, const int* __restrict__ gb) {
    int g = blockIdx.x, t = threadIdx.x;    // 512 threads
    int cnt = gb[g+1] - gb[g];
    pooled[g*1024 + t] *= 1.0f / fmaxf((float)cnt, 1.0f);
}

// ---------------- FC (K-split, float4, atomic reduce) ----------------
#define FCKZ 16
#define FCKC (1024 / FCKZ)   // 64

__global__ void k_fc_init(const float* __restrict__ b, float* __restrict__ out) {
    int i = blockIdx.x * 256 + threadIdx.x;   // 32*1024
    out[i] = b[i & 1023];
}

__global__ __launch_bounds__(256) void k_fc2(const float* __restrict__ pooled,
                                             const float* __restrict__ w,
                                             float* __restrict__ out) {
    __shared__ float pr[FCKC];
    int g = blockIdx.x;
    int z = blockIdx.y;
    int t = threadIdx.x;
    int k0 = z * FCKC;
    if (t < FCKC) pr[t] = pooled[g * 1024 + k0 + t];
    __syncthreads();
    int m0 = t * 4;
    float ax = 0.f, ay = 0.f, az = 0.f, aw = 0.f;
#pragma unroll 8
    for (int k = 0; k < FCKC; ++k) {
        const float4 wv = *(const float4*)&w[(size_t)(k0 + k) * 1024 + m0];
        float p = pr[k];
        ax += p * wv.x; ay += p * wv.y; az += p * wv.z; aw += p * wv.w;
    }
    atomicAdd(&out[g * 1024 + m0 + 0], ax);
    atomicAdd(&out[g * 1024 + m0 + 1], ay);
    atomicAdd(&out[g * 1024 + m0 + 2], az);
    atomicAdd(&out[g * 1024 + m0 + 3], aw);
}

// ---------------- host ----------------
extern "C" void kernel_launch(void* const* d_in, const int* in_sizes, int n_in,
                              void* d_out, int out_size, void* d_ws, size_t ws_size,
                              hipStream_t stream) {
    (void)in_sizes; (void)n_in; (void)out_size; (void)ws_size;
    const float* x       = (const float*)d_in[0];
    const int*   ei      = (const int*)d_in[1];
    const int*   batch   = (const int*)d_in[2];
    const float* gcn1_w  = (const float*)d_in[3];
    const float* gcn1_b  = (const float*)d_in[4];
    const float* sage_wl = (const float*)d_in[5];
    const float* sage_wr = (const float*)d_in[6];
    const float* sage_b  = (const float*)d_in[7];
    const float* gat_w   = (const float*)d_in[8];
    const float* gat_as  = (const float*)d_in[9];
    const float* gat_ad  = (const float*)d_in[10];
    const float* gat_b   = (const float*)d_in[11];
    const float* gcn4_w  = (const float*)d_in[12];
    const float* gcn4_b  = (const float*)d_in[13];
    const float* bn1_g   = (const float*)d_in[14];
    const float* bn1_b   = (const float*)d_in[15];
    const float* bn2_g   = (const float*)d_in[16];
    const float* bn2_b   = (const float*)d_in[17];
    const float* bn3_g   = (const float*)d_in[18];
    const float* bn3_b   = (const float*)d_in[19];
    const float* bn4_g   = (const float*)d_in[20];
    const float* bn4_b   = (const float*)d_in[21];
    const float* fc_w    = (const float*)d_in[22];
    const float* fc_b    = (const float*)d_in[23];
    float* out = (float*)d_out;

    char* w8 = (char*)d_ws;
    int*   indeg  = (int*)(w8 + OFF_INDEG);
    int*   rows   = (int*)(w8 + OFF_ROWS);
    int*   cursor = (int*)(w8 + OFF_CURSOR);
    int*   csr    = (int*)(w8 + OFF_CSR);
    float* dis    = (float*)(w8 + OFF_DIS);
    float* es     = (float*)(w8 + OFF_ES);
    float* ed     = (float*)(w8 + OFF_ED);
    float* bns    = (float*)(w8 + OFF_BNS);
    float* bnq    = (float*)(w8 + OFF_BNQ);
    int*   gb     = (int*)(w8 + OFF_GB);
    float* pooled = (float*)(w8 + OFF_POOL);
    float* xa1    = (float*)(w8 + OFF_XA1);
    float* h1     = (float*)(w8 + OFF_H1);
    float* agg    = (float*)(w8 + OFF_AGG);
    float* h2     = (float*)(w8 + OFF_H2);
    float* h3     = (float*)(w8 + OFF_H3);
    bf16u* hgat   = (bf16u*)(w8 + OFF_HGAT);
    bf16u* xa4b   = (bf16u*)(w8 + OFF_XA4B);
    bf16u* h2b    = (bf16u*)(w8 + OFF_H2B);
    bf16u* wT1    = (bf16u*)(w8 + OFF_WT1);
    bf16u* wT2    = (bf16u*)(w8 + OFF_WT2);
    float* h4     = (float*)(w8 + OFF_H4);

    const int* srcE = ei;        // edge_index[0,:]
    const int* dstE = ei + E_;   // edge_index[1,:]

    const int BNB = 512;
    const int BNR = N_ / BNB;

    // ---- graph structure + weight conversion ----
    hipMemsetAsync(indeg, 0, N_ * sizeof(int), stream);
    k_indeg<<<E_/256, 256, 0, stream>>>(dstE, indeg);
    k_dis<<<N_/256, 256, 0, stream>>>(indeg, dis);
    k_scan<<<1, 1024, 0, stream>>>(indeg, rows);
    hipMemcpyAsync(cursor, rows, N_ * sizeof(int), hipMemcpyDeviceToDevice, stream);
    k_fill<<<E_/256, 256, 0, stream>>>(srcE, dstE, cursor, csr);
    k_gbounds<<<1, 64, 0, stream>>>(batch, gb);
    k_wconv<<<(1024*128)/256, 256, 0, stream>>>(gat_w, wT1, 128, 1024);
    k_wconv<<<(512*256)/256, 256, 0, stream>>>(gcn4_w, wT2, 256, 512);

    // ---- layer 1: GCN 5->64, BN, ReLU ----
    k_gcn1_agg<<<N_/256, 256, 0, stream>>>(x, dis, rows, csr, xa1);
    k_mm5<<<(N_*64)/256, 256, 0, stream>>>(xa1, gcn1_w, gcn1_b, h1);
    hipMemsetAsync(bns, 0, 4096, stream);
    k_bn_stats<<<BNB, 256, 0, stream>>>(h1, bns, bnq, 64, BNR);
    k_bn_apply<<<(N_*64)/256, 256, 0, stream>>>(h1, bns, bnq, bn1_g, bn1_b, 64, N_*64, nullptr);

    // ---- layer 2: SAGE 64->128, BN, ReLU ----
    k_sage_agg<<<N_/4, 256, 0, stream>>>(h1, rows, csr, agg);
    {
        dim3 grid(128/64, N_/64);
        k_gemm<<<grid, 256, 0, stream>>>(agg, sage_wl, nullptr, h2, 64, 128, 0);
        k_gemm<<<grid, 256, 0, stream>>>(h1, sage_wr, sage_b, h2, 64, 128, 1);
    }
    hipMemsetAsync(bns, 0, 4096, stream);
    k_bn_stats<<<BNB, 256, 0, stream>>>(h2, bns, bnq, 128, BNR);
    k_bn_apply<<<(N_*128)/256, 256, 0, stream>>>(h2, bns, bnq, bn2_g, bn2_b, 128, N_*128, h2b);

    // ---- layer 3: GAT 128->4x256 (head-mean -> 256), BN, ReLU ----
    {
        dim3 grid(1024/128, N_/128);
        k_gemm_mfma<<<grid, 256, 0, stream>>>(h2b, wT1, nullptr, (float*)hgat, 128, 1024, 1);
    }
    k_gat_attn<<<N_, 256, 0, stream>>>(hgat, gat_as, gat_ad, es, ed);
    k_gat_agg<<<N_, 256, 0, stream>>>(hgat, es, ed, rows, csr, gat_b, h3);
    hipMemsetAsync(bns, 0, 4096, stream);
    k_bn_stats<<<BNB, 256, 0, stream>>>(h3, bns, bnq, 256, BNR);
    k_bn_apply<<<(N_*256)/256, 256, 0, stream>>>(h3, bns, bnq, bn3_g, bn3_b, 256, N_*256, nullptr);

    // ---- layer 4: GCN 256->512, BN, ReLU ----
    k_gcn4_agg<<<N_, 256, 0, stream>>>(h3, dis, rows, csr, xa4b);
    {
        dim3 grid(512/128, N_/128);
        k_gemm_mfma<<<grid, 256, 0, stream>>>(xa4b, wT2, gcn4_b, h4, 256, 512, 0);
    }
    hipMemsetAsync(bns, 0, 4096, stream);
    k_bn_stats<<<BNB, 256, 0, stream>>>(h4, bns, bnq, 512, BNR);
    k_bn_apply<<<(N_*512)/256, 256, 0, stream>>>(h4, bns, bnq, bn4_g, bn4_b, 512, N_*512, nullptr);

    // ---- pooling (mean | max) -> [32,1024] ----
    hipMemsetAsync(pooled, 0, 32 * 1024 * sizeof(float), stream);
    {
        dim3 grid(16, G_);
        k_pool<<<grid, 256, 0, stream>>>(h4, gb, pooled);
    }
    k_pool_fin<<<G_, 512, 0, stream>>>(pooled, gb);

    // ---- FC 1024->1024 ----
    k_fc_init<<<(G_*1024)/256, 256, 0, stream>>>(fc_b, out);
    {
        dim3 grid(G_, FCKZ);
        k_fc2<<<grid, 256, 0, stream>>>(pooled, fc_w, out);
    }
}

// Round 6
// 421.502 us; speedup vs baseline: 2.4005x; 1.1615x over previous
//
#include <hip/hip_runtime.h>

#define N_ 16384
#define E_ 131072
#define G_ 32
#define EPSF 1e-5f

typedef unsigned short bf16u;
typedef __attribute__((ext_vector_type(8))) short s8v;   // 8 bf16 (4 VGPRs)
typedef __attribute__((ext_vector_type(4))) float f4v;   // 4 fp32 acc

__device__ __forceinline__ bf16u f2bf(float v) {
    union { float f; unsigned u; } x; x.f = v;
    unsigned r = x.u + 0x7FFF + ((x.u >> 16) & 1);   // RNE
    return (bf16u)(r >> 16);
}
__device__ __forceinline__ float bf2f(bf16u u) {
    union { unsigned u; float f; } x; x.u = (unsigned)u << 16;
    return x.f;
}

// ---------------- workspace layout (bytes) ----------------
static const size_t OFF_INDEG = 0;          // int[N]
static const size_t OFF_ROWS  = 65536;      // int[N+1]
static const size_t OFF_CURSOR= 131584;     // int[N]
static const size_t OFF_CSR   = 197120;     // int[E]
static const size_t OFF_DIS   = 721408;     // float[N]
static const size_t OFF_ES    = 786944;     // float[4N]
static const size_t OFF_ED    = 1049088;    // float[4N]
static const size_t OFF_BNS   = 1311232;    // float[512]
static const size_t OFF_BNQ   = 1313280;    // float[512]
static const size_t OFF_GB    = 1315328;    // int[33]
static const size_t OFF_POOL  = 1315584;    // float[32*1024]
static const size_t OFF_XA1   = 1446656;    // float[5N]
static const size_t OFF_H1    = 1774336;    // float[64N]   4 MB
static const size_t OFF_AB    = 5968640;    // bf16[128N]   4 MB  ([agg|h1] concat)
static const size_t OFF_H2    = 10162944;   // float[128N]  8 MB
static const size_t OFF_H3B   = 18551552;   // bf16[256N]   8 MB
static const size_t OFF_HGAT  = 35328768;   // bf16[1024N]  32 MB
static const size_t OFF_XA4B  = OFF_HGAT;             // bf16[256N] 8 MB (hgat dead)
static const size_t OFF_H2B   = OFF_HGAT + 33554432;  // bf16[128N] 4 MB
static const size_t OFF_WT1   = OFF_H2B + 4194304;    // bf16[1024*128] 256 KB
static const size_t OFF_WT2   = OFF_WT1 + 262144;     // bf16[512*256]  256 KB
static const size_t OFF_WT3   = OFF_WT2 + 262144;     // bf16[128*128]  32 KB
static const size_t OFF_H4B   = OFF_HGAT + 50331648;  // bf16[512N] 16 MB
// total ≈ 100 MB

// ---------------- graph structure ----------------
__global__ void k_indeg(const int* __restrict__ dst, int* __restrict__ indeg) {
    int e = blockIdx.x * 256 + threadIdx.x;
    if (e < E_) atomicAdd(&indeg[dst[e]], 1);
}

__global__ void k_dis(const int* __restrict__ indeg, float* __restrict__ dis) {
    int i = blockIdx.x * 256 + threadIdx.x;
    if (i < N_) dis[i] = rsqrtf((float)indeg[i] + 1.0f);
}

__global__ __launch_bounds__(1024) void k_scan(const int* __restrict__ indeg,
                                               int* __restrict__ rows) {
    __shared__ int part[1024];
    int t = threadIdx.x;
    int base = t * 16;
    int local[16];
    int s = 0;
#pragma unroll
    for (int i = 0; i < 16; ++i) { local[i] = indeg[base + i]; s += local[i]; }
    part[t] = s;
    __syncthreads();
    for (int off = 1; off < 1024; off <<= 1) {
        int v = (t >= off) ? part[t - off] : 0;
        __syncthreads();
        part[t] += v;
        __syncthreads();
    }
    int run = (t == 0) ? 0 : part[t - 1];
#pragma unroll
    for (int i = 0; i < 16; ++i) { rows[base + i] = run; run += local[i]; }
    if (t == 1023) rows[N_] = run;
}

__global__ void k_fill(const int* __restrict__ src, const int* __restrict__ dst,
                       int* __restrict__ cursor, int* __restrict__ csr) {
    int e = blockIdx.x * 256 + threadIdx.x;
    if (e < E_) {
        int p = atomicAdd(&cursor[dst[e]], 1);
        csr[p] = src[e];
    }
}

__global__ void k_gbounds(const int* __restrict__ batch, int* __restrict__ gb) {
    int g = threadIdx.x;
    if (g > G_) return;
    if (g == G_) { gb[G_] = N_; return; }
    int lo = 0, hi = N_;
    while (lo < hi) { int mid = (lo + hi) >> 1; if (batch[mid] < g) lo = mid + 1; else hi = mid; }
    gb[g] = lo;
}

// ---------------- weight transpose+convert ----------------
__global__ void k_wconv(const float* __restrict__ w, bf16u* __restrict__ wT,
                        int K, int M) {
    int idx = blockIdx.x * 256 + threadIdx.x;   // M*K total
    int m = idx / K, k = idx - m * K;
    wT[idx] = f2bf(w[(size_t)k * M + m]);
}

// [wl;wr] -> wT[M=128][K=128] (k<64: wl[k][m], else wr[k-64][m])
__global__ void k_wconv_sage(const float* __restrict__ wl, const float* __restrict__ wr,
                             bf16u* __restrict__ wT) {
    int idx = blockIdx.x * 256 + threadIdx.x;   // 128*128
    int m = idx >> 7, k = idx & 127;
    float v = (k < 64) ? wl[k*128 + m] : wr[(k-64)*128 + m];
    wT[idx] = f2bf(v);
}

// ---------------- layer 1: GCN(5->64) ----------------
__global__ void k_gcn1_agg(const float* __restrict__ x, const float* __restrict__ dis,
                           const int* __restrict__ rows, const int* __restrict__ csr,
                           float* __restrict__ xa) {
    int i = blockIdx.x * 256 + threadIdx.x;
    if (i >= N_) return;
    float di = dis[i];
    float a0 = x[i*5+0]*di*di, a1 = x[i*5+1]*di*di, a2 = x[i*5+2]*di*di,
          a3 = x[i*5+3]*di*di, a4 = x[i*5+4]*di*di;
    int e0 = rows[i], e1 = rows[i+1];
    for (int e = e0; e < e1; ++e) {
        int s = csr[e];
        float w = dis[s] * di;
        a0 += x[s*5+0]*w; a1 += x[s*5+1]*w; a2 += x[s*5+2]*w;
        a3 += x[s*5+3]*w; a4 += x[s*5+4]*w;
    }
    xa[i*5+0]=a0; xa[i*5+1]=a1; xa[i*5+2]=a2; xa[i*5+3]=a3; xa[i*5+4]=a4;
}

__global__ void k_mm5(const float* __restrict__ xa, const float* __restrict__ w,
                      const float* __restrict__ b, float* __restrict__ out) {
    int idx = blockIdx.x * 256 + threadIdx.x;   // N*64
    int n = idx >> 6, m = idx & 63;
    float s = b[m];
#pragma unroll
    for (int k = 0; k < 5; ++k) s += xa[n*5+k] * w[k*64+m];
    out[idx] = s;
}

// ---------------- batchnorm stats (fp32 input) ----------------
__global__ void k_bn_stats(const float* __restrict__ x, float* __restrict__ sum,
                           float* __restrict__ sumsq, int C, int rowsPerBlock) {
    int t = threadIdx.x;
    size_t base = (size_t)blockIdx.x * rowsPerBlock * C;
    size_t end  = base + (size_t)rowsPerBlock * C;
    float s0=0,q0=0;
    for (size_t f = base + t; f < end; f += 256) {
        float v = x[f]; s0 += v; q0 += v*v;
    }
    __shared__ float ls[256], lq[256];
    ls[t]=s0; lq[t]=q0;
    __syncthreads();
    if (t < C) {
        for (int j = t + C; j < 256; j += C) { s0 += ls[j]; q0 += lq[j]; }
        atomicAdd(&sum[t], s0); atomicAdd(&sumsq[t], q0);
    }
}

// ---------------- batchnorm stats (bf16 input, C=256 or 512) ----------------
__global__ void k_bn_stats_b(const bf16u* __restrict__ x, float* __restrict__ sum,
                             float* __restrict__ sumsq, int C, int rowsPerBlock) {
    int t = threadIdx.x;
    size_t base = (size_t)blockIdx.x * rowsPerBlock * C;
    size_t end  = base + (size_t)rowsPerBlock * C;
    if (C == 512) {
        float s0=0,q0=0,s1=0,q1=0;
        for (size_t f = base + t; f < end; f += 512) {
            float v = bf2f(x[f]);     s0 += v; q0 += v*v;
            float w = bf2f(x[f+256]); s1 += w; q1 += w*w;
        }
        atomicAdd(&sum[t], s0);      atomicAdd(&sumsq[t], q0);
        atomicAdd(&sum[t+256], s1);  atomicAdd(&sumsq[t+256], q1);
    } else {  // C == 256
        float s0=0,q0=0;
        for (size_t f = base + t; f < end; f += 256) {
            float v = bf2f(x[f]); s0 += v; q0 += v*v;
        }
        atomicAdd(&sum[t], s0); atomicAdd(&sumsq[t], q0);
    }
}

// ---------------- BN apply, layer 1: fp32 in-place + bf16 mirror into ab[:,64:128] ----------------
__global__ void k_bn_apply1(float* __restrict__ h, const float* __restrict__ sum,
                            const float* __restrict__ sumsq, const float* __restrict__ g,
                            const float* __restrict__ b, bf16u* __restrict__ ab) {
    int idx = blockIdx.x * 256 + threadIdx.x;   // N*64
    int c = idx & 63, row = idx >> 6;
    const float invN = 1.0f / (float)N_;
    float mu  = sum[c] * invN;
    float var = sumsq[c] * invN - mu * mu;
    float v = (h[idx] - mu) * rsqrtf(var + EPSF) * g[c] + b[c];
    v = v > 0.f ? v : 0.f;
    h[idx] = v;
    ab[(size_t)row * 128 + 64 + c] = f2bf(v);
}

// ---------------- BN apply, layer 2: fp32 in -> bf16 out only ----------------
__global__ void k_bn_apply2(const float* __restrict__ h, const float* __restrict__ sum,
                            const float* __restrict__ sumsq, const float* __restrict__ g,
                            const float* __restrict__ b, bf16u* __restrict__ hb) {
    int idx = blockIdx.x * 256 + threadIdx.x;   // N*128
    int c = idx & 127;
    const float invN = 1.0f / (float)N_;
    float mu  = sum[c] * invN;
    float var = sumsq[c] * invN - mu * mu;
    float v = (h[idx] - mu) * rsqrtf(var + EPSF) * g[c] + b[c];
    hb[idx] = f2bf(v > 0.f ? v : 0.f);
}

// ---------------- SAGE aggregate (mean) -> bf16 into ab[:,0:64] ----------------
__global__ void k_sage_agg(const float* __restrict__ h1, const int* __restrict__ rows,
                           const int* __restrict__ csr, bf16u* __restrict__ ab) {
    int i = blockIdx.x * 4 + (threadIdx.x >> 6);
    int c = threadIdx.x & 63;
    int e0 = rows[i], e1 = rows[i+1];
    float s = 0.f;
    for (int e = e0; e < e1; ++e) s += h1[(size_t)csr[e]*64 + c];
    ab[(size_t)i*128 + c] = f2bf(s / fmaxf((float)(e1 - e0), 1.0f));
}

// ---------------- bf16 MFMA GEMM: C[n,m] = A[n,k] * BT[m,k]^T (+bias) ----------------
// 128x128 tile, BK=32, 4 waves x (4x4) mfma_f32_16x16x32_bf16 (layouts m89/m91/m120).
__global__ __launch_bounds__(256) void k_gemm_mfma(const bf16u* __restrict__ A,
                                                   const bf16u* __restrict__ BT,
                                                   const float* __restrict__ bias,
                                                   float* __restrict__ C,
                                                   int K, int M, int obf) {
    __shared__ bf16u As[128][40];
    __shared__ bf16u Bs[128][40];
    int tid = threadIdx.x;
    int wave = tid >> 6, lane = tid & 63;
    int wr = (wave >> 1) * 64, wc = (wave & 1) * 64;
    int row0 = blockIdx.y * 128, col0 = blockIdx.x * 128;
    f4v acc[4][4];
#pragma unroll
    for (int i = 0; i < 4; ++i)
#pragma unroll
        for (int j = 0; j < 4; ++j) acc[i][j] = (f4v)0.0f;

    int sr = tid >> 1;             // 0..127
    int sh = (tid & 1) * 16;       // k-half within BK
    int lr = lane & 15, lq = lane >> 4;

    for (int k0 = 0; k0 < K; k0 += 32) {
        const bf16u* ap = A + (size_t)(row0 + sr) * K + k0 + sh;
        *(uint4*)&As[sr][sh]     = *(const uint4*)ap;
        *(uint4*)&As[sr][sh + 8] = *(const uint4*)(ap + 8);
        const bf16u* bp = BT + (size_t)(col0 + sr) * K + k0 + sh;
        *(uint4*)&Bs[sr][sh]     = *(const uint4*)bp;
        *(uint4*)&Bs[sr][sh + 8] = *(const uint4*)(bp + 8);
        __syncthreads();
        s8v af[4], bfr[4];
#pragma unroll
        for (int i = 0; i < 4; ++i)
            af[i] = *(const s8v*)&As[wr + i*16 + lr][lq*8];
#pragma unroll
        for (int j = 0; j < 4; ++j)
            bfr[j] = *(const s8v*)&Bs[wc + j*16 + lr][lq*8];
#pragma unroll
        for (int i = 0; i < 4; ++i)
#pragma unroll
            for (int j = 0; j < 4; ++j)
                acc[i][j] = __builtin_amdgcn_mfma_f32_16x16x32_bf16(af[i], bfr[j], acc[i][j], 0, 0, 0);
        __syncthreads();
    }

    if (obf) {
        bf16u* Cb = (bf16u*)C;
#pragma unroll
        for (int i = 0; i < 4; ++i)
#pragma unroll
            for (int j = 0; j < 4; ++j) {
                int col = col0 + wc + j*16 + lr;
                float bv = bias ? bias[col] : 0.f;
#pragma unroll
                for (int r = 0; r < 4; ++r) {
                    int row = row0 + wr + i*16 + lq*4 + r;
                    Cb[(size_t)row * M + col] = f2bf(acc[i][j][r] + bv);
                }
            }
    } else {
#pragma unroll
        for (int i = 0; i < 4; ++i)
#pragma unroll
            for (int j = 0; j < 4; ++j) {
                int col = col0 + wc + j*16 + lr;
                float bv = bias ? bias[col] : 0.f;
#pragma unroll
                for (int r = 0; r < 4; ++r) {
                    int row = row0 + wr + i*16 + lq*4 + r;
                    C[(size_t)row * M + col] = acc[i][j][r] + bv;
                }
            }
    }
}

// ---------------- GAT attention coefficients: wave-per-node ----------------
__global__ __launch_bounds__(256) void k_gat_attn(const bf16u* __restrict__ hg,
                                                  const float* __restrict__ asrc,
                                                  const float* __restrict__ adst,
                                                  float* __restrict__ es,
                                                  float* __restrict__ ed) {
    int wave = threadIdx.x >> 6, lane = threadIdx.x & 63;
    int i = blockIdx.x * 4 + wave;
    const bf16u* hp = hg + (size_t)i*1024 + lane*4;
    float vs[4], vd[4];
#pragma unroll
    for (int h = 0; h < 4; ++h) {
        ushort4 u = *(const ushort4*)(hp + h*256);
        float4 a = *(const float4*)&asrc[h*256 + lane*4];
        float4 d = *(const float4*)&adst[h*256 + lane*4];
        float x0 = bf2f(u.x), x1 = bf2f(u.y), x2 = bf2f(u.z), x3 = bf2f(u.w);
        vs[h] = x0*a.x + x1*a.y + x2*a.z + x3*a.w;
        vd[h] = x0*d.x + x1*d.y + x2*d.z + x3*d.w;
    }
#pragma unroll
    for (int off = 32; off > 0; off >>= 1) {
#pragma unroll
        for (int h = 0; h < 4; ++h) {
            vs[h] += __shfl_xor(vs[h], off, 64);
            vd[h] += __shfl_xor(vd[h], off, 64);
        }
    }
    if (lane == 0) {
        *(float4*)&es[i*4] = make_float4(vs[0], vs[1], vs[2], vs[3]);
        *(float4*)&ed[i*4] = make_float4(vd[0], vd[1], vd[2], vd[3]);
    }
}

// ---------------- GAT aggregate (online softmax, shared exp) -> bf16 h3 ----------------
#define GCH 256
__global__ __launch_bounds__(256) void k_gat_agg(const bf16u* __restrict__ hg,
                                                 const float* __restrict__ es,
                                                 const float* __restrict__ ed,
                                                 const int* __restrict__ rows,
                                                 const int* __restrict__ csr,
                                                 const float* __restrict__ gbias,
                                                 bf16u* __restrict__ out) {
    __shared__ float4 se4[GCH];
    __shared__ int ssrc[GCH];
    int i = blockIdx.x, t = threadIdx.x;
    float edv0, edv1, edv2, edv3;
    {
        const float4 ev = *(const float4*)&ed[i*4];
        edv0 = ev.x; edv1 = ev.y; edv2 = ev.z; edv3 = ev.w;
    }
    float m0, m1, m2, m3, z0, z1, z2, z3, a0, a1, a2, a3;
    {
        const float4 sv = *(const float4*)&es[i*4];
        float e;
        e = sv.x + edv0; m0 = e >= 0.f ? e : 0.2f*e;
        e = sv.y + edv1; m1 = e >= 0.f ? e : 0.2f*e;
        e = sv.z + edv2; m2 = e >= 0.f ? e : 0.2f*e;
        e = sv.w + edv3; m3 = e >= 0.f ? e : 0.2f*e;
        z0 = z1 = z2 = z3 = 1.f;
        const bf16u* hp = hg + (size_t)i*1024 + t;
        a0 = bf2f(hp[0]); a1 = bf2f(hp[256]); a2 = bf2f(hp[512]); a3 = bf2f(hp[768]);
    }
    int e0 = rows[i], e1 = rows[i+1];
    for (int c0 = e0; c0 < e1; c0 += GCH) {
        int cn = min(GCH, e1 - c0);
        for (int j = t; j < cn; j += 256) {
            int s = csr[c0 + j];
            ssrc[j] = s;
            const float4 sv = *(const float4*)&es[s*4];
            float4 v;
            float e;
            e = sv.x + edv0; v.x = e >= 0.f ? e : 0.2f*e;
            e = sv.y + edv1; v.y = e >= 0.f ? e : 0.2f*e;
            e = sv.z + edv2; v.z = e >= 0.f ? e : 0.2f*e;
            e = sv.w + edv3; v.w = e >= 0.f ? e : 0.2f*e;
            se4[j] = v;
        }
        __syncthreads();
        float nm0 = m0, nm1 = m1, nm2 = m2, nm3 = m3;
        for (int j = 0; j < cn; ++j) {
            float4 v = se4[j];
            nm0 = fmaxf(nm0, v.x); nm1 = fmaxf(nm1, v.y);
            nm2 = fmaxf(nm2, v.z); nm3 = fmaxf(nm3, v.w);
        }
        {
            float sc;
            sc = __expf(m0 - nm0); z0 *= sc; a0 *= sc; m0 = nm0;
            sc = __expf(m1 - nm1); z1 *= sc; a1 *= sc; m1 = nm1;
            sc = __expf(m2 - nm2); z2 *= sc; a2 *= sc; m2 = nm2;
            sc = __expf(m3 - nm3); z3 *= sc; a3 *= sc; m3 = nm3;
        }
        __syncthreads();
        for (int j = t; j < cn; j += 256) {
            float4 v = se4[j];
            v.x = __expf(v.x - nm0); v.y = __expf(v.y - nm1);
            v.z = __expf(v.z - nm2); v.w = __expf(v.w - nm3);
            se4[j] = v;
        }
        __syncthreads();
        for (int j = 0; j < cn; ++j) {
            float4 ex = se4[j];
            const bf16u* hp = hg + (size_t)ssrc[j]*1024 + t;
            z0 += ex.x; a0 += ex.x * bf2f(hp[0]);
            z1 += ex.y; a1 += ex.y * bf2f(hp[256]);
            z2 += ex.z; a2 += ex.z * bf2f(hp[512]);
            z3 += ex.w; a3 += ex.w * bf2f(hp[768]);
        }
        __syncthreads();
    }
    float o = 0.25f * (a0/z0 + a1/z1 + a2/z2 + a3/z3);
    out[(size_t)i*256 + t] = f2bf(o + gbias[t]);
}

// ---------------- layer 4: fused BN3+ReLU + GCN aggregate -> bf16 ----------------
__global__ __launch_bounds__(256) void k_gcn4_agg(const bf16u* __restrict__ h3b,
                                                  const float* __restrict__ dis,
                                                  const int* __restrict__ rows,
                                                  const int* __restrict__ csr,
                                                  const float* __restrict__ sum,
                                                  const float* __restrict__ sumsq,
                                                  const float* __restrict__ g,
                                                  const float* __restrict__ b,
                                                  bf16u* __restrict__ xab) {
    int i = blockIdx.x, t = threadIdx.x;
    const float invN = 1.0f / (float)N_;
    float mu  = sum[t] * invN;
    float var = sumsq[t] * invN - mu * mu;
    float sc  = rsqrtf(var + EPSF) * g[t];
    float shf = b[t] - mu * sc;
    float di = dis[i];
    float v = fmaf(bf2f(h3b[(size_t)i*256 + t]), sc, shf);
    v = v > 0.f ? v : 0.f;
    float a = v * di * di;
    int e0 = rows[i], e1 = rows[i+1];
    for (int e = e0; e < e1; ++e) {
        int s = csr[e];
        float w = fmaf(bf2f(h3b[(size_t)s*256 + t]), sc, shf);
        w = w > 0.f ? w : 0.f;
        a += w * (dis[s] * di);
    }
    xab[(size_t)i*256 + t] = f2bf(a);
}

// ---------------- pooling with fused BN4+ReLU ----------------
__global__ void k_pool(const bf16u* __restrict__ h4b, const int* __restrict__ gb,
                       const float* __restrict__ sum, const float* __restrict__ sumsq,
                       const float* __restrict__ g, const float* __restrict__ b,
                       float* __restrict__ pooled) {
    int gi = blockIdx.y;
    int t = threadIdx.x;
    const float invN = 1.0f / (float)N_;
    float mu0 = sum[t] * invN;
    float sc0 = rsqrtf(sumsq[t] * invN - mu0*mu0 + EPSF) * g[t];
    float sh0 = b[t] - mu0 * sc0;
    float mu1 = sum[t+256] * invN;
    float sc1 = rsqrtf(sumsq[t+256] * invN - mu1*mu1 + EPSF) * g[t+256];
    float sh1 = b[t+256] - mu1 * sc1;
    int r0g = gb[gi], r1g = gb[gi+1];
    int n = r1g - r0g;
    if (n <= 0) return;
    int per = (n + 15) >> 4;
    int r0 = r0g + blockIdx.x * per;
    int r1 = min(r0 + per, r1g);
    if (r0 >= r1) return;
    float s0=0.f, s1=0.f, m0=0.f, m1=0.f;   // post-ReLU >= 0: max init 0 valid
    for (int r = r0; r < r1; ++r) {
        float v = fmaf(bf2f(h4b[(size_t)r*512 + t]), sc0, sh0);
        v = v > 0.f ? v : 0.f;
        s0 += v; m0 = fmaxf(m0, v);
        float w = fmaf(bf2f(h4b[(size_t)r*512 + 256 + t]), sc1, sh1);
        w = w > 0.f ? w : 0.f;
        s1 += w; m1 = fmaxf(m1, w);
    }
    atomicAdd(&pooled[gi*1024 + t], s0);
    atomicAdd(&pooled[gi*1024 + 256 + t], s1);
    atomicMax((int*)&pooled[gi*1024 + 512 + t],  __float_as_int(m0));
    atomicMax((int*)&pooled[gi*1024 + 768 + t],  __float_as_int(m1));
}

__global__ void k_pool_fin(float* __restrict__ pooled, const int* __restrict__ gb) {
    int g = blockIdx.x, t = threadIdx.x;    // 512 threads
    int cnt = gb[g+1] - gb[g];
    pooled[g*1024 + t] *= 1.0f / fmaxf((float)cnt, 1.0f);
}

// ---------------- FC (K-split, float4, atomic reduce) ----------------
#define FCKZ 16
#define FCKC (1024 / FCKZ)   // 64

__global__ void k_fc_init(const float* __restrict__ b, float* __restrict__ out) {
    int i = blockIdx.x * 256 + threadIdx.x;   // 32*1024
    out[i] = b[i & 1023];
}

__global__ __launch_bounds__(256) void k_fc2(const float* __restrict__ pooled,
                                             const float* __restrict__ w,
                                             float* __restrict__ out) {
    __shared__ float pr[FCKC];
    int g = blockIdx.x;
    int z = blockIdx.y;
    int t = threadIdx.x;
    int k0 = z * FCKC;
    if (t < FCKC) pr[t] = pooled[g * 1024 + k0 + t];
    __syncthreads();
    int m0 = t * 4;
    float ax = 0.f, ay = 0.f, az = 0.f, aw = 0.f;
#pragma unroll 8
    for (int k = 0; k < FCKC; ++k) {
        const float4 wv = *(const float4*)&w[(size_t)(k0 + k) * 1024 + m0];
        float p = pr[k];
        ax += p * wv.x; ay += p * wv.y; az += p * wv.z; aw += p * wv.w;
    }
    atomicAdd(&out[g * 1024 + m0 + 0], ax);
    atomicAdd(&out[g * 1024 + m0 + 1], ay);
    atomicAdd(&out[g * 1024 + m0 + 2], az);
    atomicAdd(&out[g * 1024 + m0 + 3], aw);
}

// ---------------- host ----------------
extern "C" void kernel_launch(void* const* d_in, const int* in_sizes, int n_in,
                              void* d_out, int out_size, void* d_ws, size_t ws_size,
                              hipStream_t stream) {
    (void)in_sizes; (void)n_in; (void)out_size; (void)ws_size;
    const float* x       = (const float*)d_in[0];
    const int*   ei      = (const int*)d_in[1];
    const int*   batch   = (const int*)d_in[2];
    const float* gcn1_w  = (const float*)d_in[3];
    const float* gcn1_b  = (const float*)d_in[4];
    const float* sage_wl = (const float*)d_in[5];
    const float* sage_wr = (const float*)d_in[6];
    const float* sage_b  = (const float*)d_in[7];
    const float* gat_w   = (const float*)d_in[8];
    const float* gat_as  = (const float*)d_in[9];
    const float* gat_ad  = (const float*)d_in[10];
    const float* gat_b   = (const float*)d_in[11];
    const float* gcn4_w  = (const float*)d_in[12];
    const float* gcn4_b  = (const float*)d_in[13];
    const float* bn1_g   = (const float*)d_in[14];
    const float* bn1_b   = (const float*)d_in[15];
    const float* bn2_g   = (const float*)d_in[16];
    const float* bn2_b   = (const float*)d_in[17];
    const float* bn3_g   = (const float*)d_in[18];
    const float* bn3_b   = (const float*)d_in[19];
    const float* bn4_g   = (const float*)d_in[20];
    const float* bn4_b   = (const float*)d_in[21];
    const float* fc_w    = (const float*)d_in[22];
    const float* fc_b    = (const float*)d_in[23];
    float* out = (float*)d_out;

    char* w8 = (char*)d_ws;
    int*   indeg  = (int*)(w8 + OFF_INDEG);
    int*   rows   = (int*)(w8 + OFF_ROWS);
    int*   cursor = (int*)(w8 + OFF_CURSOR);
    int*   csr    = (int*)(w8 + OFF_CSR);
    float* dis    = (float*)(w8 + OFF_DIS);
    float* es     = (float*)(w8 + OFF_ES);
    float* ed     = (float*)(w8 + OFF_ED);
    float* bns    = (float*)(w8 + OFF_BNS);
    float* bnq    = (float*)(w8 + OFF_BNQ);
    int*   gb     = (int*)(w8 + OFF_GB);
    float* pooled = (float*)(w8 + OFF_POOL);
    float* xa1    = (float*)(w8 + OFF_XA1);
    float* h1     = (float*)(w8 + OFF_H1);
    bf16u* ab     = (bf16u*)(w8 + OFF_AB);
    float* h2     = (float*)(w8 + OFF_H2);
    bf16u* h3b    = (bf16u*)(w8 + OFF_H3B);
    bf16u* hgat   = (bf16u*)(w8 + OFF_HGAT);
    bf16u* xa4b   = (bf16u*)(w8 + OFF_XA4B);
    bf16u* h2b    = (bf16u*)(w8 + OFF_H2B);
    bf16u* wT1    = (bf16u*)(w8 + OFF_WT1);
    bf16u* wT2    = (bf16u*)(w8 + OFF_WT2);
    bf16u* wT3    = (bf16u*)(w8 + OFF_WT3);
    bf16u* h4b    = (bf16u*)(w8 + OFF_H4B);

    const int* srcE = ei;        // edge_index[0,:]
    const int* dstE = ei + E_;   // edge_index[1,:]

    const int BNB = 512;
    const int BNR = N_ / BNB;

    // ---- graph structure + weight conversion ----
    hipMemsetAsync(indeg, 0, N_ * sizeof(int), stream);
    k_indeg<<<E_/256, 256, 0, stream>>>(dstE, indeg);
    k_dis<<<N_/256, 256, 0, stream>>>(indeg, dis);
    k_scan<<<1, 1024, 0, stream>>>(indeg, rows);
    hipMemcpyAsync(cursor, rows, N_ * sizeof(int), hipMemcpyDeviceToDevice, stream);
    k_fill<<<E_/256, 256, 0, stream>>>(srcE, dstE, cursor, csr);
    k_gbounds<<<1, 64, 0, stream>>>(batch, gb);
    k_wconv<<<(1024*128)/256, 256, 0, stream>>>(gat_w, wT1, 128, 1024);
    k_wconv<<<(512*256)/256, 256, 0, stream>>>(gcn4_w, wT2, 256, 512);
    k_wconv_sage<<<(128*128)/256, 256, 0, stream>>>(sage_wl, sage_wr, wT3);

    // ---- layer 1: GCN 5->64, BN, ReLU ----
    k_gcn1_agg<<<N_/256, 256, 0, stream>>>(x, dis, rows, csr, xa1);
    k_mm5<<<(N_*64)/256, 256, 0, stream>>>(xa1, gcn1_w, gcn1_b, h1);
    hipMemsetAsync(bns, 0, 4096, stream);
    k_bn_stats<<<BNB, 256, 0, stream>>>(h1, bns, bnq, 64, BNR);
    k_bn_apply1<<<(N_*64)/256, 256, 0, stream>>>(h1, bns, bnq, bn1_g, bn1_b, ab);

    // ---- layer 2: SAGE 64->128 via single MFMA GEMM on [agg|h1], BN, ReLU ----
    k_sage_agg<<<N_/4, 256, 0, stream>>>(h1, rows, csr, ab);
    {
        dim3 grid(1, N_/128);
        k_gemm_mfma<<<grid, 256, 0, stream>>>(ab, wT3, sage_b, h2, 128, 128, 0);
    }
    hipMemsetAsync(bns, 0, 4096, stream);
    k_bn_stats<<<BNB, 256, 0, stream>>>(h2, bns, bnq, 128, BNR);
    k_bn_apply2<<<(N_*128)/256, 256, 0, stream>>>(h2, bns, bnq, bn2_g, bn2_b, h2b);

    // ---- layer 3: GAT 128->4x256 (head-mean -> 256) ----
    {
        dim3 grid(1024/128, N_/128);
        k_gemm_mfma<<<grid, 256, 0, stream>>>(h2b, wT1, nullptr, (float*)hgat, 128, 1024, 1);
    }
    k_gat_attn<<<N_/4, 256, 0, stream>>>(hgat, gat_as, gat_ad, es, ed);
    k_gat_agg<<<N_, 256, 0, stream>>>(hgat, es, ed, rows, csr, gat_b, h3b);
    hipMemsetAsync(bns, 0, 4096, stream);
    k_bn_stats_b<<<BNB, 256, 0, stream>>>(h3b, bns, bnq, 256, BNR);

    // ---- layer 4: fused BN3+ReLU+aggregate, MFMA GEMM 256->512 (bf16 out) ----
    k_gcn4_agg<<<N_, 256, 0, stream>>>(h3b, dis, rows, csr, bns, bnq, bn3_g, bn3_b, xa4b);
    {
        dim3 grid(512/128, N_/128);
        k_gemm_mfma<<<grid, 256, 0, stream>>>(xa4b, wT2, gcn4_b, (float*)h4b, 256, 512, 1);
    }
    hipMemsetAsync(bns, 0, 4096, stream);
    k_bn_stats_b<<<BNB, 256, 0, stream>>>(h4b, bns, bnq, 512, BNR);

    // ---- pooling with fused BN4+ReLU -> [32,1024] ----
    hipMemsetAsync(pooled, 0, 32 * 1024 * sizeof(float), stream);
    {
        dim3 grid(16, G_);
        k_pool<<<grid, 256, 0, stream>>>(h4b, gb, bns, bnq, bn4_g, bn4_b, pooled);
    }
    k_pool_fin<<<G_, 512, 0, stream>>>(pooled, gb);

    // ---- FC 1024->1024 ----
    k_fc_init<<<(G_*1024)/256, 256, 0, stream>>>(fc_b, out);
    {
        dim3 grid(G_, FCKZ);
        k_fc2<<<grid, 256, 0, stream>>>(pooled, fc_w, out);
    }
}